// Round 4
// baseline (1121.224 us; speedup 1.0000x reference)
//
#include <hip/hip_runtime.h>
#include <math.h>

constexpr int B_ = 32, T_ = 512, N_ = 7, BN_ = 224;
constexpr int L_ = 64, DM_ = 32, PLEN_ = 16;
constexpr int HF_ = 256, NH_ = 8, DFF_ = 32;
constexpr int S_ = 1000, DLLM_ = 4096, V_ = 32000;
constexpr int PRED_ = 96, HNF_ = 2048;
constexpr int KSPLIT2 = 8, KCH2 = 4000;  // GEMM2 split-K

typedef short bf16x8 __attribute__((ext_vector_type(8)));
typedef float f32x4 __attribute__((ext_vector_type(4)));

__device__ inline ushort f2bf(float x) {
    union { float f; uint u; } v; v.f = x;
    uint r = v.u + 0x7fffu + ((v.u >> 16) & 1u);  // RNE
    return (ushort)(r >> 16);
}
__device__ inline uint pk(float a, float b) {
    return (uint)f2bf(a) | ((uint)f2bf(b) << 16);
}

// ---------------- stats: mean/stdev per (b,n) ----------------
__global__ __launch_bounds__(256) void k_stats(const float* __restrict__ x,
                                               float* __restrict__ mean_o,
                                               float* __restrict__ std_o) {
    int bn = blockIdx.x, b = bn / N_, n = bn % N_;
    const float* xp = x + (size_t)b * T_ * N_ + n;
    float s = 0.f, sq = 0.f;
    for (int t = threadIdx.x; t < T_; t += 256) { float v = xp[(size_t)t * N_]; s += v; sq += v * v; }
    for (int o = 32; o > 0; o >>= 1) { s += __shfl_down(s, o, 64); sq += __shfl_down(sq, o, 64); }
    __shared__ float rs[4], rq[4];
    int wid = threadIdx.x >> 6, lane = threadIdx.x & 63;
    if (lane == 0) { rs[wid] = s; rq[wid] = sq; }
    __syncthreads();
    if (threadIdx.x == 0) {
        float S = rs[0] + rs[1] + rs[2] + rs[3];
        float Q = rq[0] + rq[1] + rq[2] + rq[3];
        float m = S / T_;
        float var = Q / T_ - m * m;
        mean_o[bn] = m;
        std_o[bn] = sqrtf(var + 1e-5f);
    }
}

// ---------------- wsum[c] = sum_d wkv[c][d] (exact f32, for map_b folding) ----------------
__global__ __launch_bounds__(256) void k_wsum(const float* __restrict__ wk,
                                              const float* __restrict__ wv,
                                              float* __restrict__ wsum) {
    int c = blockIdx.x;
    const float* row = (c < HF_) ? wk + (size_t)c * DLLM_ : wv + (size_t)(c - HF_) * DLLM_;
    float s = 0.f;
    for (int d = threadIdx.x; d < DLLM_; d += 256) s += row[d];
    for (int o = 32; o > 0; o >>= 1) s += __shfl_down(s, o, 64);
    __shared__ float rs[4];
    int wid = threadIdx.x >> 6, lane = threadIdx.x & 63;
    if (lane == 0) rs[wid] = s;
    __syncthreads();
    if (threadIdx.x == 0) wsum[c] = rs[0] + rs[1] + rs[2] + rs[3];
}

// ---------------- normalize + patch + conv embed ----------------
__global__ __launch_bounds__(256) void k_enc(const float* __restrict__ x,
                                             const float* __restrict__ conv_w,
                                             const float* __restrict__ mean_i,
                                             const float* __restrict__ std_i,
                                             float* __restrict__ enc) {
    int bn = blockIdx.x, b = bn / N_, n = bn % N_;
    __shared__ float xn[520];
    __shared__ float cw[DM_ * PLEN_ * 3];
    float m = mean_i[bn], rstd = 1.0f / std_i[bn];
    for (int i = threadIdx.x; i < DM_ * PLEN_ * 3; i += 256) cw[i] = conv_w[i];
    const float* xp = x + (size_t)b * T_ * N_ + n;
    for (int t = threadIdx.x; t < T_; t += 256) xn[t] = (xp[(size_t)t * N_] - m) * rstd;
    __syncthreads();
    if (threadIdx.x < 8) xn[T_ + threadIdx.x] = xn[T_ - 1];
    __syncthreads();
    for (int idx = threadIdx.x; idx < L_ * DM_; idx += 256) {
        int l = idx >> 5, o = idx & 31;
        float acc = 0.f;
        #pragma unroll
        for (int t = 0; t < 3; t++) {
            int col = l + t;
            int pcol = (col == 0) ? 63 : ((col == 65) ? 0 : col - 1);
            const float* xb = &xn[pcol * 8];
            const float* cwb = &cw[o * 48 + t];
            #pragma unroll
            for (int i = 0; i < 16; i++) acc += xb[i] * cwb[i * 3];
        }
        enc[(size_t)bn * 2048 + idx] = acc;
    }
}

// ---------------- q = (enc @ wq^T + bq) * scale ----------------
__global__ __launch_bounds__(256) void k_q(const float* __restrict__ enc,
                                           const float* __restrict__ wq,
                                           const float* __restrict__ bq,
                                           float* __restrict__ qo) {
    int bn = blockIdx.x;
    __shared__ float et[2048];
    __shared__ float wqs[HF_ * DM_];
    for (int i = threadIdx.x; i < 2048; i += 256) et[i] = enc[(size_t)bn * 2048 + i];
    for (int i = threadIdx.x; i < HF_ * DM_; i += 256) wqs[i] = wq[i];
    __syncthreads();
    const float scale = 0.17677669529663687f;
    for (int idx = threadIdx.x; idx < L_ * HF_; idx += 256) {
        int l = idx >> 8, c = idx & 255;
        float acc = bq[c];
        const float* e = &et[l * 32];
        const float* w = &wqs[c * 32];
        #pragma unroll
        for (int k = 0; k < 32; k++) acc += e[k] * w[k];
        qo[(size_t)bn * L_ * HF_ + idx] = acc * scale;
    }
}

// ---------------- cvt wk,wv -> wkv_bf [512][4096] bf16 ----------------
__global__ __launch_bounds__(256) void k_cvt_wkv(const float* __restrict__ wk,
                                                 const float* __restrict__ wv,
                                                 ushort* __restrict__ out) {
    int g = blockIdx.x * 256 + threadIdx.x;
    int e = g * 8;
    const float* src = (e < HF_ * DLLM_) ? wk + e : wv + (e - HF_ * DLLM_);
    float4 x = *(const float4*)src, y = *(const float4*)(src + 4);
    uint4 w; w.x = pk(x.x, x.y); w.y = pk(x.z, x.w); w.z = pk(y.x, y.y); w.w = pk(y.z, y.w);
    *(uint4*)(out + e) = w;
}

// ---------------- GEMM1 (bf16 MFMA): E_T[512][32000] = (word_emb @ wkv^T)^T ----------------
// BM=128, BN=256, BK=32, 512 threads (8 waves 2x4, 64x64/wave).
// A: f32->bf16 via LDS (contiguous 16B-stride writes). B: direct global->reg (L2-resident).
__global__ __launch_bounds__(512) void k_gemm1(const float* __restrict__ A,
                                               const ushort* __restrict__ Bw,
                                               ushort* __restrict__ ET) {
    __shared__ union {
        ushort A2[2][128 * 32];   // 16 KB
        ushort C[256 * 72];       // 36 KB epilogue transpose
    } lds;
    const int tid = threadIdx.x;
    const int lane = tid & 63, wid = tid >> 6;
    const int wr = wid >> 2, wc = wid & 3;
    const int m0 = blockIdx.x * 128, n0 = blockIdx.y * 256;

    // A stager: thread t -> row t>>2, k-octet t&3 (8 f32 -> 8 bf16 = 16 B at byte tid*16)
    const float* aptr = A + (size_t)(m0 + (tid >> 2)) * DLLM_ + (tid & 3) * 8;

    // B per-lane row pointers (4 frags, 16 rows x 4 k-octets per frag)
    const ushort* bp0 = Bw + (size_t)(n0 + wc * 64 + 0  + (lane & 15)) * DLLM_ + (lane >> 4) * 8;
    const ushort* bp1 = Bw + (size_t)(n0 + wc * 64 + 16 + (lane & 15)) * DLLM_ + (lane >> 4) * 8;
    const ushort* bp2 = Bw + (size_t)(n0 + wc * 64 + 32 + (lane & 15)) * DLLM_ + (lane >> 4) * 8;
    const ushort* bp3 = Bw + (size_t)(n0 + wc * 64 + 48 + (lane & 15)) * DLLM_ + (lane >> 4) * 8;

    f32x4 acc[4][4];
    #pragma unroll
    for (int i = 0; i < 4; i++)
        #pragma unroll
        for (int j = 0; j < 4; j++) acc[i][j] = (f32x4){0.f, 0.f, 0.f, 0.f};

    {   // prologue: stage A tile 0
        float4 a0 = *(const float4*)aptr;
        float4 a1 = *(const float4*)(aptr + 4);
        uint4 wa; wa.x = pk(a0.x, a0.y); wa.y = pk(a0.z, a0.w); wa.z = pk(a1.x, a1.y); wa.w = pk(a1.z, a1.w);
        *(uint4*)&lds.A2[0][tid * 8] = wa;
    }
    bf16x8 bcur[4];
    bcur[0] = *(const bf16x8*)bp0; bcur[1] = *(const bf16x8*)bp1;
    bcur[2] = *(const bf16x8*)bp2; bcur[3] = *(const bf16x8*)bp3;
    __syncthreads();

    int cur = 0;
    constexpr int NT = DLLM_ / 32;  // 128
    for (int t = 0; t < NT; ++t) {
        const bool more = (t + 1 < NT);
        float4 a0, a1;
        bf16x8 bnext[4];
        if (more) {
            const float* ap = aptr + (t + 1) * 32;
            a0 = *(const float4*)ap; a1 = *(const float4*)(ap + 4);
            const int o = (t + 1) * 32;
            bnext[0] = *(const bf16x8*)(bp0 + o); bnext[1] = *(const bf16x8*)(bp1 + o);
            bnext[2] = *(const bf16x8*)(bp2 + o); bnext[3] = *(const bf16x8*)(bp3 + o);
        }
        const ushort* Ab = lds.A2[cur];
        bf16x8 af[4];
        #pragma unroll
        for (int mi = 0; mi < 4; mi++)
            af[mi] = *(const bf16x8*)&Ab[(wr * 64 + mi * 16 + (lane & 15)) * 32 + (lane >> 4) * 8];
        #pragma unroll
        for (int mi = 0; mi < 4; mi++)
            #pragma unroll
            for (int ni = 0; ni < 4; ni++)
                acc[mi][ni] = __builtin_amdgcn_mfma_f32_16x16x32_bf16(af[mi], bcur[ni], acc[mi][ni], 0, 0, 0);
        if (more) {
            uint4 wa; wa.x = pk(a0.x, a0.y); wa.y = pk(a0.z, a0.w); wa.z = pk(a1.x, a1.y); wa.w = pk(a1.z, a1.w);
            *(uint4*)&lds.A2[cur ^ 1][tid * 8] = wa;
            bcur[0] = bnext[0]; bcur[1] = bnext[1]; bcur[2] = bnext[2]; bcur[3] = bnext[3];
        }
        __syncthreads();
        cur ^= 1;
    }

    // epilogue: transpose to E_T via LDS, two rounds over wr halves
    #pragma unroll
    for (int p = 0; p < 2; p++) {
        __syncthreads();
        if (wr == p) {
            #pragma unroll
            for (int mi = 0; mi < 4; mi++)
                #pragma unroll
                for (int ni = 0; ni < 4; ni++) {
                    int nl = wc * 64 + ni * 16 + (lane & 15);
                    int ml = mi * 16 + (lane >> 4) * 4;
                    uint2 w2;
                    w2.x = pk(acc[mi][ni][0], acc[mi][ni][1]);
                    w2.y = pk(acc[mi][ni][2], acc[mi][ni][3]);
                    *(uint2*)&lds.C[nl * 72 + ml] = w2;
                }
        }
        __syncthreads();
        {
            int r = tid >> 1, half = tid & 1;
            const uint4* src = (const uint4*)&lds.C[r * 72 + half * 32];
            ushort* dst = ET + (size_t)(n0 + r) * V_ + m0 + p * 64 + half * 32;
            uint4 v0 = src[0], v1 = src[1], v2 = src[2], v3 = src[3];
            *(uint4*)(dst + 0) = v0; *(uint4*)(dst + 8) = v1;
            *(uint4*)(dst + 16) = v2; *(uint4*)(dst + 24) = v3;
        }
    }
}

// ---------------- GEMM2 (bf16 MFMA, split-K): Cp[kz] = map_w[:,chunk] @ E_T[:,chunk]^T ----------------
// BM=128, BN=128, BK=32, 256 threads (4 waves 2x2, 64x64/wave). A via LDS, B direct-to-reg.
__global__ __launch_bounds__(256) void k_gemm2(const float* __restrict__ A,
                                               const ushort* __restrict__ ET,
                                               float* __restrict__ Cp) {
    __shared__ ushort As[2][128 * 32];   // 16 KB
    const int tid = threadIdx.x, lane = tid & 63, wid = tid >> 6;
    const int wr = wid >> 1, wc = wid & 1;
    const int m0 = blockIdx.x * 128, n0 = blockIdx.y * 128, kz = blockIdx.z;
    const size_t kbase = (size_t)kz * KCH2;

    // A stager: two contiguous passes; pass p covers chunk c = p*256+tid -> row c>>2, oct c&3
    const int r0 = m0 + (tid >> 2), r1 = r0 + 64;
    const bool v0 = r0 < S_, v1 = r1 < S_;
    const float* ap0 = A + (size_t)r0 * V_ + kbase + (tid & 3) * 8;
    const float* ap1 = A + (size_t)r1 * V_ + kbase + (tid & 3) * 8;

    const ushort* bp0 = ET + (size_t)(n0 + wc * 64 + 0  + (lane & 15)) * V_ + kbase + (lane >> 4) * 8;
    const ushort* bp1 = ET + (size_t)(n0 + wc * 64 + 16 + (lane & 15)) * V_ + kbase + (lane >> 4) * 8;
    const ushort* bp2 = ET + (size_t)(n0 + wc * 64 + 32 + (lane & 15)) * V_ + kbase + (lane >> 4) * 8;
    const ushort* bp3 = ET + (size_t)(n0 + wc * 64 + 48 + (lane & 15)) * V_ + kbase + (lane >> 4) * 8;

    f32x4 acc[4][4];
    #pragma unroll
    for (int i = 0; i < 4; i++)
        #pragma unroll
        for (int j = 0; j < 4; j++) acc[i][j] = (f32x4){0.f, 0.f, 0.f, 0.f};

    {   // prologue
        float4 z = {0.f, 0.f, 0.f, 0.f};
        float4 a0 = v0 ? *(const float4*)ap0 : z, a1 = v0 ? *(const float4*)(ap0 + 4) : z;
        float4 a2 = v1 ? *(const float4*)ap1 : z, a3 = v1 ? *(const float4*)(ap1 + 4) : z;
        uint4 w0, w1;
        w0.x = pk(a0.x, a0.y); w0.y = pk(a0.z, a0.w); w0.z = pk(a1.x, a1.y); w0.w = pk(a1.z, a1.w);
        w1.x = pk(a2.x, a2.y); w1.y = pk(a2.z, a2.w); w1.z = pk(a3.x, a3.y); w1.w = pk(a3.z, a3.w);
        *(uint4*)&As[0][tid * 8] = w0;
        *(uint4*)&As[0][(256 + tid) * 8] = w1;
    }
    bf16x8 bcur[4];
    bcur[0] = *(const bf16x8*)bp0; bcur[1] = *(const bf16x8*)bp1;
    bcur[2] = *(const bf16x8*)bp2; bcur[3] = *(const bf16x8*)bp3;
    __syncthreads();

    int cur = 0;
    constexpr int NT = KCH2 / 32;  // 125
    for (int t = 0; t < NT; ++t) {
        const bool more = (t + 1 < NT);
        float4 a0, a1, a2, a3;
        bf16x8 bnext[4];
        if (more) {
            float4 z = {0.f, 0.f, 0.f, 0.f};
            const int o = (t + 1) * 32;
            a0 = v0 ? *(const float4*)(ap0 + o) : z; a1 = v0 ? *(const float4*)(ap0 + o + 4) : z;
            a2 = v1 ? *(const float4*)(ap1 + o) : z; a3 = v1 ? *(const float4*)(ap1 + o + 4) : z;
            bnext[0] = *(const bf16x8*)(bp0 + o); bnext[1] = *(const bf16x8*)(bp1 + o);
            bnext[2] = *(const bf16x8*)(bp2 + o); bnext[3] = *(const bf16x8*)(bp3 + o);
        }
        const ushort* Ab = As[cur];
        bf16x8 af[4];
        #pragma unroll
        for (int mi = 0; mi < 4; mi++)
            af[mi] = *(const bf16x8*)&Ab[(wr * 64 + mi * 16 + (lane & 15)) * 32 + (lane >> 4) * 8];
        #pragma unroll
        for (int mi = 0; mi < 4; mi++)
            #pragma unroll
            for (int ni = 0; ni < 4; ni++)
                acc[mi][ni] = __builtin_amdgcn_mfma_f32_16x16x32_bf16(af[mi], bcur[ni], acc[mi][ni], 0, 0, 0);
        if (more) {
            uint4 w0, w1;
            w0.x = pk(a0.x, a0.y); w0.y = pk(a0.z, a0.w); w0.z = pk(a1.x, a1.y); w0.w = pk(a1.z, a1.w);
            w1.x = pk(a2.x, a2.y); w1.y = pk(a2.z, a2.w); w1.z = pk(a3.x, a3.y); w1.w = pk(a3.z, a3.w);
            *(uint4*)&As[cur ^ 1][tid * 8] = w0;
            *(uint4*)&As[cur ^ 1][(256 + tid) * 8] = w1;
            bcur[0] = bnext[0]; bcur[1] = bnext[1]; bcur[2] = bnext[2]; bcur[3] = bnext[3];
        }
        __syncthreads();
        cur ^= 1;
    }

    #pragma unroll
    for (int mi = 0; mi < 4; mi++)
        #pragma unroll
        for (int ni = 0; ni < 4; ni++)
            #pragma unroll
            for (int j = 0; j < 4; j++) {
                int m = m0 + wr * 64 + mi * 16 + (lane >> 4) * 4 + j;
                int n = n0 + wc * 64 + ni * 16 + (lane & 15);
                if (m < S_) Cp[((size_t)kz * S_ + m) * 512 + n] = acc[mi][ni][j];
            }
}

// ---------------- reduce split-K + exact bias ----------------
__global__ __launch_bounds__(256) void k_red(const float* __restrict__ Cp,
                                             const float* __restrict__ mb,
                                             const float* __restrict__ wsum,
                                             const float* __restrict__ bk,
                                             const float* __restrict__ bv,
                                             float* __restrict__ KV) {
    int idx = blockIdx.x * 256 + threadIdx.x;
    if (idx >= S_ * 512) return;
    int m = idx >> 9, n = idx & 511;
    float s = 0.f;
    #pragma unroll
    for (int z = 0; z < KSPLIT2; z++) s += Cp[(size_t)z * S_ * 512 + idx];
    float bias = (n < HF_) ? bk[n] : bv[n - HF_];
    KV[idx] = s + mb[m] * wsum[n] + bias;
}

// ---------------- flash attention per (h, bn) ----------------
constexpr int TS = 128;
__global__ __launch_bounds__(256) void k_attn(const float* __restrict__ q,
                                              const float* __restrict__ kv,
                                              float* __restrict__ rep) {
    const int h = blockIdx.x, bn = blockIdx.y;
    __shared__ float Ks[TS][36];
    __shared__ float Vs[TS][36];
    __shared__ float sm[4][64][2];
    __shared__ float buf[64][33];
    const int tid = threadIdx.x;
    const int l = tid & 63, wid = tid >> 6;

    float qreg[32];
    const float* qp = q + ((size_t)bn * L_ + l) * HF_ + h * 32;
    #pragma unroll
    for (int e = 0; e < 32; e += 4) {
        float4 v = *(const float4*)(qp + e);
        qreg[e] = v.x; qreg[e + 1] = v.y; qreg[e + 2] = v.z; qreg[e + 3] = v.w;
    }

    float m = -1e30f, sum = 0.f;
    float acc[32] = {};

    for (int s0 = 0; s0 < S_; s0 += TS) {
        for (int idx = tid; idx < TS * 8; idx += 256) {
            int r = idx >> 3, c4 = (idx & 7) * 4;
            int s = s0 + r;
            float4 kx = make_float4(0.f, 0.f, 0.f, 0.f);
            float4 vx = kx;
            if (s < S_) {
                kx = *(const float4*)(kv + (size_t)s * 512 + h * 32 + c4);
                vx = *(const float4*)(kv + (size_t)s * 512 + 256 + h * 32 + c4);
            }
            *(float4*)&Ks[r][c4] = kx;
            *(float4*)&Vs[r][c4] = vx;
        }
        __syncthreads();

        const int sbase = wid * 32;
        float sc[32];
        #pragma unroll 4
        for (int j = 0; j < 32; j++) {
            int sg = s0 + sbase + j;
            float d = 0.f;
            const float* kr = &Ks[sbase + j][0];
            #pragma unroll
            for (int e = 0; e < 32; e++) d += qreg[e] * kr[e];
            sc[j] = (sg < S_) ? d : -1e30f;
        }
        float tmax = -1e30f;
        #pragma unroll
        for (int j = 0; j < 32; j++) tmax = fmaxf(tmax, sc[j]);
        float mnew = fmaxf(m, tmax);
        float rescale = __expf(m - mnew);
        sum *= rescale;
        #pragma unroll
        for (int e = 0; e < 32; e++) acc[e] *= rescale;
        #pragma unroll 2
        for (int j = 0; j < 32; j++) {
            float p = __expf(sc[j] - mnew);
            sum += p;
            const float* vr = &Vs[sbase + j][0];
            #pragma unroll
            for (int e = 0; e < 32; e++) acc[e] += p * vr[e];
        }
        m = mnew;
        __syncthreads();
    }

    sm[wid][l][0] = m;
    sm[wid][l][1] = sum;
    __syncthreads();
    float gm = fmaxf(fmaxf(sm[0][l][0], sm[1][l][0]), fmaxf(sm[2][l][0], sm[3][l][0]));
    float gden = 0.f;
    #pragma unroll
    for (int w = 0; w < 4; w++) gden += sm[w][l][1] * __expf(sm[w][l][0] - gm);
    float f = __expf(m - gm) / gden;
    for (int i = tid; i < 64 * 33; i += 256) ((float*)buf)[i] = 0.f;
    __syncthreads();
    for (int w = 0; w < 4; w++) {
        if (wid == w) {
            #pragma unroll
            for (int e = 0; e < 32; e++) buf[l][e] += acc[e] * f;
        }
        __syncthreads();
    }
    for (int idx = tid; idx < 2048; idx += 256) {
        int ll = idx & 63, e = idx >> 6;
        rep[((size_t)bn * HF_ + h * 32 + e) * 64 + ll] = buf[ll][e];
    }
}

// ---------------- out32 = rep @ wo[0:32]^T + bo ----------------
__global__ __launch_bounds__(256) void k_out(const float* __restrict__ rep,
                                             const float* __restrict__ wo,
                                             const float* __restrict__ bo,
                                             float* __restrict__ out32) {
    const int bn = blockIdx.x;
    __shared__ float woT[HF_][32];
    const int tid = threadIdx.x;
    for (int idx = tid; idx < HF_ * 32; idx += 256) {
        int e = idx & 31, c = idx >> 5;
        woT[c][e] = wo[(size_t)e * HF_ + c];
    }
    __syncthreads();
    const int l = tid & 63, e0 = (tid >> 6) * 8;
    float acc[8];
    #pragma unroll
    for (int i = 0; i < 8; i++) acc[i] = bo[e0 + i];
    const float* rp = rep + (size_t)bn * HF_ * 64 + l;
    for (int c = 0; c < HF_; c++) {
        float rv = rp[(size_t)c * 64];
        #pragma unroll
        for (int i = 0; i < 8; i++) acc[i] += rv * woT[c][e0 + i];
    }
    float* op = out32 + ((size_t)bn * L_ + l) * 32 + e0;
    #pragma unroll
    for (int i = 0; i < 8; i++) op[i] = acc[i];
}

// ---------------- head GEMM + de-normalize ----------------
__global__ __launch_bounds__(256) void k_head(const float* __restrict__ out32,
                                              const float* __restrict__ hw,
                                              const float* __restrict__ hb,
                                              const float* __restrict__ mean_i,
                                              const float* __restrict__ std_i,
                                              float* __restrict__ out) {
    int bn = blockIdx.x, b = bn / N_, n = bn % N_;
    __shared__ float dt[2048];
    for (int i = threadIdx.x; i < 2048; i += 256) dt[i] = out32[(size_t)bn * 2048 + i];
    __syncthreads();
    float m = mean_i[bn], sd = std_i[bn];
    for (int p = threadIdx.x; p < PRED_; p += 256) {
        float acc = hb[p];
        const float* w = hw + (size_t)p * HNF_;
        for (int f = 0; f < DFF_; f++) {
            const float* wf = w + f * 64;
            #pragma unroll
            for (int ll = 0; ll < 64; ll++) acc += dt[ll * 32 + f] * wf[ll];
        }
        out[(size_t)b * PRED_ * N_ + (size_t)p * N_ + n] = acc * sd + m;
    }
}

extern "C" void kernel_launch(void* const* d_in, const int* in_sizes, int n_in,
                              void* d_out, int out_size, void* d_ws, size_t ws_size,
                              hipStream_t stream) {
    const float* x_enc   = (const float*)d_in[0];
    const float* conv_w  = (const float*)d_in[1];
    const float* word_emb= (const float*)d_in[2];
    const float* map_w   = (const float*)d_in[3];
    const float* map_b   = (const float*)d_in[4];
    const float* wq      = (const float*)d_in[5];
    const float* bq      = (const float*)d_in[6];
    const float* wk      = (const float*)d_in[7];
    const float* bk      = (const float*)d_in[8];
    const float* wv      = (const float*)d_in[9];
    const float* bv      = (const float*)d_in[10];
    const float* wo      = (const float*)d_in[11];
    const float* bo      = (const float*)d_in[12];
    const float* head_w  = (const float*)d_in[13];
    const float* head_b  = (const float*)d_in[14];

    float* ws = (float*)d_ws;
    float* mean_w = ws;                          // 256
    float* std_w  = ws + 256;                    // 256
    float* wsum_w = ws + 512;                    // 512
    float* enc_w  = ws + 1024;                   // 224*2048
    float* q_w    = enc_w + (size_t)BN_ * 2048;  // 224*16384
    float* kv_w   = q_w + (size_t)BN_ * L_ * HF_;// 1000*512
    float* o32_w  = kv_w + (size_t)S_ * 512;     // 224*2048
    float* cp_w   = o32_w + (size_t)BN_ * 2048;  // 8*1000*512
    float* rep_w  = cp_w;                        // alias: cp dead after k_red
    ushort* et_w  = (ushort*)(cp_w + (size_t)KSPLIT2 * S_ * 512);  // 512*32000 bf16
    ushort* wkv_w = et_w + (size_t)512 * V_;                       // 512*4096 bf16

    k_stats<<<BN_, 256, 0, stream>>>(x_enc, mean_w, std_w);
    k_wsum<<<512, 256, 0, stream>>>(wk, wv, wsum_w);
    k_enc<<<BN_, 256, 0, stream>>>(x_enc, conv_w, mean_w, std_w, enc_w);
    k_q<<<BN_, 256, 0, stream>>>(enc_w, wq, bq, q_w);
    k_cvt_wkv<<<(512 * DLLM_ / 8) / 256, 256, 0, stream>>>(wk, wv, wkv_w);
    k_gemm1<<<dim3(V_ / 128, 2), 512, 0, stream>>>(word_emb, wkv_w, et_w);
    k_gemm2<<<dim3(8, 4, KSPLIT2), 256, 0, stream>>>(map_w, et_w, cp_w);
    k_red<<<(S_ * 512 + 255) / 256, 256, 0, stream>>>(cp_w, map_b, wsum_w, bk, bv, kv_w);
    k_attn<<<dim3(NH_, BN_), 256, 0, stream>>>(q_w, kv_w, rep_w);
    k_out<<<BN_, 256, 0, stream>>>(rep_w, wo, bo, o32_w);
    k_head<<<BN_, 256, 0, stream>>>(o32_w, head_w, head_b, mean_w, std_w, (float*)d_out);
}

// Round 5
// 897.723 us; speedup vs baseline: 1.2490x; 1.2490x over previous
//
#include <hip/hip_runtime.h>
#include <math.h>

constexpr int B_ = 32, T_ = 512, N_ = 7, BN_ = 224;
constexpr int L_ = 64, DM_ = 32, PLEN_ = 16;
constexpr int HF_ = 256, NH_ = 8, DFF_ = 32;
constexpr int S_ = 1000, DLLM_ = 4096, V_ = 32000;
constexpr int PRED_ = 96, HNF_ = 2048;
constexpr int KSPLIT2 = 8, KCH2 = 4000;  // GEMM2 split-K

typedef short bf16x8 __attribute__((ext_vector_type(8)));
typedef float f32x4 __attribute__((ext_vector_type(4)));

__device__ inline ushort f2bf(float x) {
    union { float f; uint u; } v; v.f = x;
    uint r = v.u + 0x7fffu + ((v.u >> 16) & 1u);  // RNE
    return (ushort)(r >> 16);
}
__device__ inline uint pk(float a, float b) {
    return (uint)f2bf(a) | ((uint)f2bf(b) << 16);
}
__device__ inline void gl16(const void* g, void* l) {
    __builtin_amdgcn_global_load_lds(
        (const __attribute__((address_space(1))) void*)g,
        (__attribute__((address_space(3))) void*)l, 16, 0, 0);
}

// ---------------- stats: mean/stdev per (b,n) ----------------
__global__ __launch_bounds__(256) void k_stats(const float* __restrict__ x,
                                               float* __restrict__ mean_o,
                                               float* __restrict__ std_o) {
    int bn = blockIdx.x, b = bn / N_, n = bn % N_;
    const float* xp = x + (size_t)b * T_ * N_ + n;
    float s = 0.f, sq = 0.f;
    for (int t = threadIdx.x; t < T_; t += 256) { float v = xp[(size_t)t * N_]; s += v; sq += v * v; }
    for (int o = 32; o > 0; o >>= 1) { s += __shfl_down(s, o, 64); sq += __shfl_down(sq, o, 64); }
    __shared__ float rs[4], rq[4];
    int wid = threadIdx.x >> 6, lane = threadIdx.x & 63;
    if (lane == 0) { rs[wid] = s; rq[wid] = sq; }
    __syncthreads();
    if (threadIdx.x == 0) {
        float S = rs[0] + rs[1] + rs[2] + rs[3];
        float Q = rq[0] + rq[1] + rq[2] + rq[3];
        float m = S / T_;
        float var = Q / T_ - m * m;
        mean_o[bn] = m;
        std_o[bn] = sqrtf(var + 1e-5f);
    }
}

// ---------------- wsum[c] = sum_d wkv[c][d] (exact f32, for map_b folding) ----------------
__global__ __launch_bounds__(256) void k_wsum(const float* __restrict__ wk,
                                              const float* __restrict__ wv,
                                              float* __restrict__ wsum) {
    int c = blockIdx.x;
    const float* row = (c < HF_) ? wk + (size_t)c * DLLM_ : wv + (size_t)(c - HF_) * DLLM_;
    float s = 0.f;
    for (int d = threadIdx.x; d < DLLM_; d += 256) s += row[d];
    for (int o = 32; o > 0; o >>= 1) s += __shfl_down(s, o, 64);
    __shared__ float rs[4];
    int wid = threadIdx.x >> 6, lane = threadIdx.x & 63;
    if (lane == 0) rs[wid] = s;
    __syncthreads();
    if (threadIdx.x == 0) wsum[c] = rs[0] + rs[1] + rs[2] + rs[3];
}

// ---------------- normalize + patch + conv embed ----------------
__global__ __launch_bounds__(256) void k_enc(const float* __restrict__ x,
                                             const float* __restrict__ conv_w,
                                             const float* __restrict__ mean_i,
                                             const float* __restrict__ std_i,
                                             float* __restrict__ enc) {
    int bn = blockIdx.x, b = bn / N_, n = bn % N_;
    __shared__ float xn[520];
    __shared__ float cw[DM_ * PLEN_ * 3];
    float m = mean_i[bn], rstd = 1.0f / std_i[bn];
    for (int i = threadIdx.x; i < DM_ * PLEN_ * 3; i += 256) cw[i] = conv_w[i];
    const float* xp = x + (size_t)b * T_ * N_ + n;
    for (int t = threadIdx.x; t < T_; t += 256) xn[t] = (xp[(size_t)t * N_] - m) * rstd;
    __syncthreads();
    if (threadIdx.x < 8) xn[T_ + threadIdx.x] = xn[T_ - 1];
    __syncthreads();
    for (int idx = threadIdx.x; idx < L_ * DM_; idx += 256) {
        int l = idx >> 5, o = idx & 31;
        float acc = 0.f;
        #pragma unroll
        for (int t = 0; t < 3; t++) {
            int col = l + t;
            int pcol = (col == 0) ? 63 : ((col == 65) ? 0 : col - 1);
            const float* xb = &xn[pcol * 8];
            const float* cwb = &cw[o * 48 + t];
            #pragma unroll
            for (int i = 0; i < 16; i++) acc += xb[i] * cwb[i * 3];
        }
        enc[(size_t)bn * 2048 + idx] = acc;
    }
}

// ---------------- q = (enc @ wq^T + bq) * scale ----------------
__global__ __launch_bounds__(256) void k_q(const float* __restrict__ enc,
                                           const float* __restrict__ wq,
                                           const float* __restrict__ bq,
                                           float* __restrict__ qo) {
    int bn = blockIdx.x;
    __shared__ float et[2048];
    __shared__ float wqs[HF_ * DM_];
    for (int i = threadIdx.x; i < 2048; i += 256) et[i] = enc[(size_t)bn * 2048 + i];
    for (int i = threadIdx.x; i < HF_ * DM_; i += 256) wqs[i] = wq[i];
    __syncthreads();
    const float scale = 0.17677669529663687f;
    for (int idx = threadIdx.x; idx < L_ * HF_; idx += 256) {
        int l = idx >> 8, c = idx & 255;
        float acc = bq[c];
        const float* e = &et[l * 32];
        const float* w = &wqs[c * 32];
        #pragma unroll
        for (int k = 0; k < 32; k++) acc += e[k] * w[k];
        qo[(size_t)bn * L_ * HF_ + idx] = acc * scale;
    }
}

// ---------------- cvt wk,wv -> wkv_bf [512][4096] bf16 ----------------
__global__ __launch_bounds__(256) void k_cvt_wkv(const float* __restrict__ wk,
                                                 const float* __restrict__ wv,
                                                 ushort* __restrict__ out) {
    int g = blockIdx.x * 256 + threadIdx.x;
    int e = g * 8;
    const float* src = (e < HF_ * DLLM_) ? wk + e : wv + (e - HF_ * DLLM_);
    float4 x = *(const float4*)src, y = *(const float4*)(src + 4);
    uint4 w; w.x = pk(x.x, x.y); w.y = pk(x.z, x.w); w.z = pk(y.x, y.y); w.w = pk(y.z, y.w);
    *(uint4*)(out + e) = w;
}

// ---------------- GEMM1 (bf16 MFMA): E_T[512][32000] = (word_emb @ wkv^T)^T ----------------
// BM=128, BN=256, BK=32, 512 threads (8 waves 2x4, 64x64/wave).
// A: f32->bf16 reg-pack, swizzled LDS write. B: global_load_lds w/ pre-swizzled source.
// Swizzle: 16B unit of (row r, oct o) lives at u = 4r + (o ^ ((r>>1)&3)) -> 2-way (free) banks.
__global__ __launch_bounds__(512) void k_gemm1(const float* __restrict__ A,
                                               const ushort* __restrict__ Bw,
                                               ushort* __restrict__ ET) {
    __shared__ union {
        struct { ushort A[2][128 * 32]; ushort B[2][256 * 32]; } st;  // 48 KB
        ushort C[256 * 72];                                           // 36 KB epilogue
    } lds;
    const int tid = threadIdx.x;
    const int lane = tid & 63, wid = tid >> 6;
    const int wr = wid >> 2, wc = wid & 3;
    const int n0 = blockIdx.x * 256, m0 = blockIdx.y * 128;

    // A stager: thread t -> row t>>2, oct t&3; swizzled unit
    const int ar = tid >> 2, ao = tid & 3;
    const int au = (ar << 2) | (ao ^ ((ar >> 1) & 3));
    const float* aptr = A + (size_t)(m0 + ar) * DLLM_ + ao * 8;

    // B stager: units u0=tid, u1=tid+512; source octet pre-swizzled
    const int u0 = tid, rb0 = u0 >> 2, ob0 = (u0 & 3) ^ ((rb0 >> 1) & 3);
    const int u1 = tid + 512, rb1 = u1 >> 2, ob1 = (u1 & 3) ^ ((rb1 >> 1) & 3);
    const ushort* bptr0 = Bw + (size_t)(n0 + rb0) * DLLM_ + ob0 * 8;
    const ushort* bptr1 = Bw + (size_t)(n0 + rb1) * DLLM_ + ob1 * 8;

    // fragment read: row r=base+rl, swizzled oct
    const int rl = lane & 15;
    const int oc = (lane >> 4) ^ ((rl >> 1) & 3);

    f32x4 acc[4][4];
    #pragma unroll
    for (int i = 0; i < 4; i++)
        #pragma unroll
        for (int j = 0; j < 4; j++) acc[i][j] = (f32x4){0.f, 0.f, 0.f, 0.f};

    {   // prologue: stage tile 0
        gl16(bptr0, &lds.st.B[0][u0 * 8]);
        gl16(bptr1, &lds.st.B[0][u1 * 8]);
        float4 a0 = *(const float4*)aptr;
        float4 a1 = *(const float4*)(aptr + 4);
        uint4 wa; wa.x = pk(a0.x, a0.y); wa.y = pk(a0.z, a0.w); wa.z = pk(a1.x, a1.y); wa.w = pk(a1.z, a1.w);
        *(uint4*)&lds.st.A[0][au * 8] = wa;
    }
    __syncthreads();

    int cur = 0;
    constexpr int NT = DLLM_ / 32;  // 128
    for (int t = 0; t < NT; ++t) {
        const bool more = (t + 1 < NT);
        float4 a0, a1;
        if (more) {
            const int o = (t + 1) * 32;
            gl16(bptr0 + o, &lds.st.B[cur ^ 1][u0 * 8]);
            gl16(bptr1 + o, &lds.st.B[cur ^ 1][u1 * 8]);
            const float* ap = aptr + o;
            a0 = *(const float4*)ap; a1 = *(const float4*)(ap + 4);
        }
        const ushort* Ab = lds.st.A[cur];
        const ushort* Bb = lds.st.B[cur];
        bf16x8 af[4], bfr[4];
        #pragma unroll
        for (int mi = 0; mi < 4; mi++)
            af[mi] = *(const bf16x8*)&Ab[(wr * 64 + mi * 16 + rl) * 32 + oc * 8];
        #pragma unroll
        for (int ni = 0; ni < 4; ni++)
            bfr[ni] = *(const bf16x8*)&Bb[(wc * 64 + ni * 16 + rl) * 32 + oc * 8];
        #pragma unroll
        for (int mi = 0; mi < 4; mi++)
            #pragma unroll
            for (int ni = 0; ni < 4; ni++)
                acc[mi][ni] = __builtin_amdgcn_mfma_f32_16x16x32_bf16(af[mi], bfr[ni], acc[mi][ni], 0, 0, 0);
        if (more) {
            uint4 wa; wa.x = pk(a0.x, a0.y); wa.y = pk(a0.z, a0.w); wa.z = pk(a1.x, a1.y); wa.w = pk(a1.z, a1.w);
            *(uint4*)&lds.st.A[cur ^ 1][au * 8] = wa;
        }
        __syncthreads();
        cur ^= 1;
    }

    // epilogue: transpose to E_T via LDS, two rounds over wr halves
    #pragma unroll
    for (int p = 0; p < 2; p++) {
        __syncthreads();
        if (wr == p) {
            #pragma unroll
            for (int mi = 0; mi < 4; mi++)
                #pragma unroll
                for (int ni = 0; ni < 4; ni++) {
                    int nl = wc * 64 + ni * 16 + (lane & 15);
                    int ml = mi * 16 + (lane >> 4) * 4;
                    uint2 w2;
                    w2.x = pk(acc[mi][ni][0], acc[mi][ni][1]);
                    w2.y = pk(acc[mi][ni][2], acc[mi][ni][3]);
                    *(uint2*)&lds.C[nl * 72 + ml] = w2;
                }
        }
        __syncthreads();
        {
            int r = tid >> 1, half = tid & 1;
            const uint4* src = (const uint4*)&lds.C[r * 72 + half * 32];
            ushort* dst = ET + (size_t)(n0 + r) * V_ + m0 + p * 64 + half * 32;
            uint4 v0 = src[0], v1 = src[1], v2 = src[2], v3 = src[3];
            *(uint4*)(dst + 0) = v0; *(uint4*)(dst + 8) = v1;
            *(uint4*)(dst + 16) = v2; *(uint4*)(dst + 24) = v3;
        }
    }
}

// ---------------- GEMM2 (bf16 MFMA, split-K): Cp[kz] = map_w[:,chunk] @ E_T[:,chunk]^T ----------------
// BM=128, BN=128, BK=32, 256 threads (4 waves 2x2, 64x64/wave). Same swizzled staging.
__global__ __launch_bounds__(256) void k_gemm2(const float* __restrict__ A,
                                               const ushort* __restrict__ ET,
                                               float* __restrict__ Cp) {
    __shared__ ushort As[2][128 * 32];   // 16 KB
    __shared__ ushort Bs[2][128 * 32];   // 16 KB
    const int tid = threadIdx.x, lane = tid & 63, wid = tid >> 6;
    const int wr = wid >> 1, wc = wid & 1;
    const int m0 = blockIdx.x * 128, n0 = blockIdx.y * 128, kz = blockIdx.z;
    const size_t kbase = (size_t)kz * KCH2;

    // A stager: thread t -> (row t>>2, oct t&3) and (row+64, oct); same swizzle key
    const int ar = tid >> 2, ao = tid & 3;
    const int au = (ar << 2) | (ao ^ ((ar >> 1) & 3));   // second unit = au + 256
    const int r0 = m0 + ar, r1 = r0 + 64;
    const bool v0 = r0 < S_, v1 = r1 < S_;
    const float* ap0 = A + (size_t)r0 * V_ + kbase + ao * 8;
    const float* ap1 = A + (size_t)r1 * V_ + kbase + ao * 8;

    // B stager: units u0=tid, u1=tid+256 via gload_lds, pre-swizzled source
    const int u0 = tid, rb0 = u0 >> 2, ob0 = (u0 & 3) ^ ((rb0 >> 1) & 3);
    const int u1 = tid + 256, rb1 = u1 >> 2, ob1 = (u1 & 3) ^ ((rb1 >> 1) & 3);
    const ushort* bp0 = ET + (size_t)(n0 + rb0) * V_ + kbase + ob0 * 8;
    const ushort* bp1 = ET + (size_t)(n0 + rb1) * V_ + kbase + ob1 * 8;

    const int rl = lane & 15;
    const int oc = (lane >> 4) ^ ((rl >> 1) & 3);

    f32x4 acc[4][4];
    #pragma unroll
    for (int i = 0; i < 4; i++)
        #pragma unroll
        for (int j = 0; j < 4; j++) acc[i][j] = (f32x4){0.f, 0.f, 0.f, 0.f};

    {   // prologue
        gl16(bp0, &Bs[0][u0 * 8]);
        gl16(bp1, &Bs[0][u1 * 8]);
        float4 z = {0.f, 0.f, 0.f, 0.f};
        float4 a0 = v0 ? *(const float4*)ap0 : z, a1 = v0 ? *(const float4*)(ap0 + 4) : z;
        float4 a2 = v1 ? *(const float4*)ap1 : z, a3 = v1 ? *(const float4*)(ap1 + 4) : z;
        uint4 w0, w1;
        w0.x = pk(a0.x, a0.y); w0.y = pk(a0.z, a0.w); w0.z = pk(a1.x, a1.y); w0.w = pk(a1.z, a1.w);
        w1.x = pk(a2.x, a2.y); w1.y = pk(a2.z, a2.w); w1.z = pk(a3.x, a3.y); w1.w = pk(a3.z, a3.w);
        *(uint4*)&As[0][au * 8] = w0;
        *(uint4*)&As[0][(au + 256) * 8] = w1;
    }
    __syncthreads();

    int cur = 0;
    constexpr int NT = KCH2 / 32;  // 125
    for (int t = 0; t < NT; ++t) {
        const bool more = (t + 1 < NT);
        float4 a0, a1, a2, a3;
        if (more) {
            const int o = (t + 1) * 32;
            gl16(bp0 + o, &Bs[cur ^ 1][u0 * 8]);
            gl16(bp1 + o, &Bs[cur ^ 1][u1 * 8]);
            float4 z = {0.f, 0.f, 0.f, 0.f};
            a0 = v0 ? *(const float4*)(ap0 + o) : z; a1 = v0 ? *(const float4*)(ap0 + o + 4) : z;
            a2 = v1 ? *(const float4*)(ap1 + o) : z; a3 = v1 ? *(const float4*)(ap1 + o + 4) : z;
        }
        const ushort* Ab = As[cur];
        const ushort* Bb = Bs[cur];
        bf16x8 af[4], bfr[4];
        #pragma unroll
        for (int mi = 0; mi < 4; mi++)
            af[mi] = *(const bf16x8*)&Ab[(wr * 64 + mi * 16 + rl) * 32 + oc * 8];
        #pragma unroll
        for (int ni = 0; ni < 4; ni++)
            bfr[ni] = *(const bf16x8*)&Bb[(wc * 64 + ni * 16 + rl) * 32 + oc * 8];
        #pragma unroll
        for (int mi = 0; mi < 4; mi++)
            #pragma unroll
            for (int ni = 0; ni < 4; ni++)
                acc[mi][ni] = __builtin_amdgcn_mfma_f32_16x16x32_bf16(af[mi], bfr[ni], acc[mi][ni], 0, 0, 0);
        if (more) {
            uint4 w0, w1;
            w0.x = pk(a0.x, a0.y); w0.y = pk(a0.z, a0.w); w0.z = pk(a1.x, a1.y); w0.w = pk(a1.z, a1.w);
            w1.x = pk(a2.x, a2.y); w1.y = pk(a2.z, a2.w); w1.z = pk(a3.x, a3.y); w1.w = pk(a3.z, a3.w);
            *(uint4*)&As[cur ^ 1][au * 8] = w0;
            *(uint4*)&As[cur ^ 1][(au + 256) * 8] = w1;
        }
        __syncthreads();
        cur ^= 1;
    }

    #pragma unroll
    for (int mi = 0; mi < 4; mi++)
        #pragma unroll
        for (int ni = 0; ni < 4; ni++)
            #pragma unroll
            for (int j = 0; j < 4; j++) {
                int m = m0 + wr * 64 + mi * 16 + (lane >> 4) * 4 + j;
                int n = n0 + wc * 64 + ni * 16 + (lane & 15);
                if (m < S_) Cp[((size_t)kz * S_ + m) * 512 + n] = acc[mi][ni][j];
            }
}

// ---------------- reduce split-K + exact bias ----------------
__global__ __launch_bounds__(256) void k_red(const float* __restrict__ Cp,
                                             const float* __restrict__ mb,
                                             const float* __restrict__ wsum,
                                             const float* __restrict__ bk,
                                             const float* __restrict__ bv,
                                             float* __restrict__ KV) {
    int idx = blockIdx.x * 256 + threadIdx.x;
    if (idx >= S_ * 512) return;
    int m = idx >> 9, n = idx & 511;
    float s = 0.f;
    #pragma unroll
    for (int z = 0; z < KSPLIT2; z++) s += Cp[(size_t)z * S_ * 512 + idx];
    float bias = (n < HF_) ? bk[n] : bv[n - HF_];
    KV[idx] = s + mb[m] * wsum[n] + bias;
}

// ---------------- flash attention per (h, bn) ----------------
constexpr int TS = 128;
__global__ __launch_bounds__(256) void k_attn(const float* __restrict__ q,
                                              const float* __restrict__ kv,
                                              float* __restrict__ rep) {
    const int h = blockIdx.x, bn = blockIdx.y;
    __shared__ float Ks[TS][36];
    __shared__ float Vs[TS][36];
    __shared__ float sm[4][64][2];
    __shared__ float buf[64][33];
    const int tid = threadIdx.x;
    const int l = tid & 63, wid = tid >> 6;

    float qreg[32];
    const float* qp = q + ((size_t)bn * L_ + l) * HF_ + h * 32;
    #pragma unroll
    for (int e = 0; e < 32; e += 4) {
        float4 v = *(const float4*)(qp + e);
        qreg[e] = v.x; qreg[e + 1] = v.y; qreg[e + 2] = v.z; qreg[e + 3] = v.w;
    }

    float m = -1e30f, sum = 0.f;
    float acc[32] = {};

    for (int s0 = 0; s0 < S_; s0 += TS) {
        for (int idx = tid; idx < TS * 8; idx += 256) {
            int r = idx >> 3, c4 = (idx & 7) * 4;
            int s = s0 + r;
            float4 kx = make_float4(0.f, 0.f, 0.f, 0.f);
            float4 vx = kx;
            if (s < S_) {
                kx = *(const float4*)(kv + (size_t)s * 512 + h * 32 + c4);
                vx = *(const float4*)(kv + (size_t)s * 512 + 256 + h * 32 + c4);
            }
            *(float4*)&Ks[r][c4] = kx;
            *(float4*)&Vs[r][c4] = vx;
        }
        __syncthreads();

        const int sbase = wid * 32;
        float sc[32];
        #pragma unroll 4
        for (int j = 0; j < 32; j++) {
            int sg = s0 + sbase + j;
            float d = 0.f;
            const float* kr = &Ks[sbase + j][0];
            #pragma unroll
            for (int e = 0; e < 32; e++) d += qreg[e] * kr[e];
            sc[j] = (sg < S_) ? d : -1e30f;
        }
        float tmax = -1e30f;
        #pragma unroll
        for (int j = 0; j < 32; j++) tmax = fmaxf(tmax, sc[j]);
        float mnew = fmaxf(m, tmax);
        float rescale = __expf(m - mnew);
        sum *= rescale;
        #pragma unroll
        for (int e = 0; e < 32; e++) acc[e] *= rescale;
        #pragma unroll 2
        for (int j = 0; j < 32; j++) {
            float p = __expf(sc[j] - mnew);
            sum += p;
            const float* vr = &Vs[sbase + j][0];
            #pragma unroll
            for (int e = 0; e < 32; e++) acc[e] += p * vr[e];
        }
        m = mnew;
        __syncthreads();
    }

    sm[wid][l][0] = m;
    sm[wid][l][1] = sum;
    __syncthreads();
    float gm = fmaxf(fmaxf(sm[0][l][0], sm[1][l][0]), fmaxf(sm[2][l][0], sm[3][l][0]));
    float gden = 0.f;
    #pragma unroll
    for (int w = 0; w < 4; w++) gden += sm[w][l][1] * __expf(sm[w][l][0] - gm);
    float f = __expf(m - gm) / gden;
    for (int i = tid; i < 64 * 33; i += 256) ((float*)buf)[i] = 0.f;
    __syncthreads();
    for (int w = 0; w < 4; w++) {
        if (wid == w) {
            #pragma unroll
            for (int e = 0; e < 32; e++) buf[l][e] += acc[e] * f;
        }
        __syncthreads();
    }
    for (int idx = tid; idx < 2048; idx += 256) {
        int ll = idx & 63, e = idx >> 6;
        rep[((size_t)bn * HF_ + h * 32 + e) * 64 + ll] = buf[ll][e];
    }
}

// ---------------- out32 = rep @ wo[0:32]^T + bo ----------------
__global__ __launch_bounds__(256) void k_out(const float* __restrict__ rep,
                                             const float* __restrict__ wo,
                                             const float* __restrict__ bo,
                                             float* __restrict__ out32) {
    const int bn = blockIdx.x;
    __shared__ float woT[HF_][32];
    const int tid = threadIdx.x;
    for (int idx = tid; idx < HF_ * 32; idx += 256) {
        int e = idx & 31, c = idx >> 5;
        woT[c][e] = wo[(size_t)e * HF_ + c];
    }
    __syncthreads();
    const int l = tid & 63, e0 = (tid >> 6) * 8;
    float acc[8];
    #pragma unroll
    for (int i = 0; i < 8; i++) acc[i] = bo[e0 + i];
    const float* rp = rep + (size_t)bn * HF_ * 64 + l;
    for (int c = 0; c < HF_; c++) {
        float rv = rp[(size_t)c * 64];
        #pragma unroll
        for (int i = 0; i < 8; i++) acc[i] += rv * woT[c][e0 + i];
    }
    float* op = out32 + ((size_t)bn * L_ + l) * 32 + e0;
    #pragma unroll
    for (int i = 0; i < 8; i++) op[i] = acc[i];
}

// ---------------- head GEMM + de-normalize ----------------
__global__ __launch_bounds__(256) void k_head(const float* __restrict__ out32,
                                              const float* __restrict__ hw,
                                              const float* __restrict__ hb,
                                              const float* __restrict__ mean_i,
                                              const float* __restrict__ std_i,
                                              float* __restrict__ out) {
    int bn = blockIdx.x, b = bn / N_, n = bn % N_;
    __shared__ float dt[2048];
    for (int i = threadIdx.x; i < 2048; i += 256) dt[i] = out32[(size_t)bn * 2048 + i];
    __syncthreads();
    float m = mean_i[bn], sd = std_i[bn];
    for (int p = threadIdx.x; p < PRED_; p += 256) {
        float acc = hb[p];
        const float* w = hw + (size_t)p * HNF_;
        for (int f = 0; f < DFF_; f++) {
            const float* wf = w + f * 64;
            #pragma unroll
            for (int ll = 0; ll < 64; ll++) acc += dt[ll * 32 + f] * wf[ll];
        }
        out[(size_t)b * PRED_ * N_ + (size_t)p * N_ + n] = acc * sd + m;
    }
}

extern "C" void kernel_launch(void* const* d_in, const int* in_sizes, int n_in,
                              void* d_out, int out_size, void* d_ws, size_t ws_size,
                              hipStream_t stream) {
    const float* x_enc   = (const float*)d_in[0];
    const float* conv_w  = (const float*)d_in[1];
    const float* word_emb= (const float*)d_in[2];
    const float* map_w   = (const float*)d_in[3];
    const float* map_b   = (const float*)d_in[4];
    const float* wq      = (const float*)d_in[5];
    const float* bq      = (const float*)d_in[6];
    const float* wk      = (const float*)d_in[7];
    const float* bk      = (const float*)d_in[8];
    const float* wv      = (const float*)d_in[9];
    const float* bv      = (const float*)d_in[10];
    const float* wo      = (const float*)d_in[11];
    const float* bo      = (const float*)d_in[12];
    const float* head_w  = (const float*)d_in[13];
    const float* head_b  = (const float*)d_in[14];

    float* ws = (float*)d_ws;
    float* mean_w = ws;                          // 256
    float* std_w  = ws + 256;                    // 256
    float* wsum_w = ws + 512;                    // 512
    float* enc_w  = ws + 1024;                   // 224*2048
    float* q_w    = enc_w + (size_t)BN_ * 2048;  // 224*16384
    float* kv_w   = q_w + (size_t)BN_ * L_ * HF_;// 1000*512
    float* o32_w  = kv_w + (size_t)S_ * 512;     // 224*2048
    float* cp_w   = o32_w + (size_t)BN_ * 2048;  // 8*1000*512
    float* rep_w  = cp_w;                        // alias: cp dead after k_red
    ushort* et_w  = (ushort*)(cp_w + (size_t)KSPLIT2 * S_ * 512);  // 512*32000 bf16
    ushort* wkv_w = et_w + (size_t)512 * V_;                       // 512*4096 bf16

    k_stats<<<BN_, 256, 0, stream>>>(x_enc, mean_w, std_w);
    k_wsum<<<512, 256, 0, stream>>>(wk, wv, wsum_w);
    k_enc<<<BN_, 256, 0, stream>>>(x_enc, conv_w, mean_w, std_w, enc_w);
    k_q<<<BN_, 256, 0, stream>>>(enc_w, wq, bq, q_w);
    k_cvt_wkv<<<(512 * DLLM_ / 8) / 256, 256, 0, stream>>>(wk, wv, wkv_w);
    k_gemm1<<<dim3(2, V_ / 128), 512, 0, stream>>>(word_emb, wkv_w, et_w);
    k_gemm2<<<dim3(8, 4, KSPLIT2), 256, 0, stream>>>(map_w, et_w, cp_w);
    k_red<<<(S_ * 512 + 255) / 256, 256, 0, stream>>>(cp_w, map_b, wsum_w, bk, bv, kv_w);
    k_attn<<<dim3(NH_, BN_), 256, 0, stream>>>(q_w, kv_w, rep_w);
    k_out<<<BN_, 256, 0, stream>>>(rep_w, wo, bo, o32_w);
    k_head<<<BN_, 256, 0, stream>>>(o32_w, head_w, head_b, mean_w, std_w, (float*)d_out);
}

// Round 6
// 745.282 us; speedup vs baseline: 1.5044x; 1.2045x over previous
//
#include <hip/hip_runtime.h>
#include <math.h>

constexpr int B_ = 32, T_ = 512, N_ = 7, BN_ = 224;
constexpr int L_ = 64, DM_ = 32, PLEN_ = 16;
constexpr int HF_ = 256, NH_ = 8, DFF_ = 32;
constexpr int S_ = 1000, DLLM_ = 4096, V_ = 32000;
constexpr int PRED_ = 96, HNF_ = 2048;
constexpr int KSPLIT2 = 25, KCH2 = 1280;  // GEMM2 split-K: 25 * 1280 = 32000

typedef short bf16x8 __attribute__((ext_vector_type(8)));
typedef float f32x4 __attribute__((ext_vector_type(4)));

__device__ inline ushort f2bf(float x) {
    union { float f; uint u; } v; v.f = x;
    uint r = v.u + 0x7fffu + ((v.u >> 16) & 1u);  // RNE
    return (ushort)(r >> 16);
}
__device__ inline uint pk(float a, float b) {
    return (uint)f2bf(a) | ((uint)f2bf(b) << 16);
}
__device__ inline void gl16(const void* g, void* l) {
    __builtin_amdgcn_global_load_lds(
        (const __attribute__((address_space(1))) void*)g,
        (__attribute__((address_space(3))) void*)l, 16, 0, 0);
}

// ---------------- stats: mean/stdev per (b,n) ----------------
__global__ __launch_bounds__(256) void k_stats(const float* __restrict__ x,
                                               float* __restrict__ mean_o,
                                               float* __restrict__ std_o) {
    int bn = blockIdx.x, b = bn / N_, n = bn % N_;
    const float* xp = x + (size_t)b * T_ * N_ + n;
    float s = 0.f, sq = 0.f;
    for (int t = threadIdx.x; t < T_; t += 256) { float v = xp[(size_t)t * N_]; s += v; sq += v * v; }
    for (int o = 32; o > 0; o >>= 1) { s += __shfl_down(s, o, 64); sq += __shfl_down(sq, o, 64); }
    __shared__ float rs[4], rq[4];
    int wid = threadIdx.x >> 6, lane = threadIdx.x & 63;
    if (lane == 0) { rs[wid] = s; rq[wid] = sq; }
    __syncthreads();
    if (threadIdx.x == 0) {
        float S = rs[0] + rs[1] + rs[2] + rs[3];
        float Q = rq[0] + rq[1] + rq[2] + rq[3];
        float m = S / T_;
        float var = Q / T_ - m * m;
        mean_o[bn] = m;
        std_o[bn] = sqrtf(var + 1e-5f);
    }
}

// ---------------- wsum[c] = sum_d wkv[c][d] (exact f32, for map_b folding) ----------------
__global__ __launch_bounds__(256) void k_wsum(const float* __restrict__ wk,
                                              const float* __restrict__ wv,
                                              float* __restrict__ wsum) {
    int c = blockIdx.x;
    const float* row = (c < HF_) ? wk + (size_t)c * DLLM_ : wv + (size_t)(c - HF_) * DLLM_;
    float s = 0.f;
    for (int d = threadIdx.x; d < DLLM_; d += 256) s += row[d];
    for (int o = 32; o > 0; o >>= 1) s += __shfl_down(s, o, 64);
    __shared__ float rs[4];
    int wid = threadIdx.x >> 6, lane = threadIdx.x & 63;
    if (lane == 0) rs[wid] = s;
    __syncthreads();
    if (threadIdx.x == 0) wsum[c] = rs[0] + rs[1] + rs[2] + rs[3];
}

// ---------------- normalize + patch + conv embed ----------------
__global__ __launch_bounds__(256) void k_enc(const float* __restrict__ x,
                                             const float* __restrict__ conv_w,
                                             const float* __restrict__ mean_i,
                                             const float* __restrict__ std_i,
                                             float* __restrict__ enc) {
    int bn = blockIdx.x, b = bn / N_, n = bn % N_;
    __shared__ float xn[520];
    __shared__ float cw[DM_ * PLEN_ * 3];
    float m = mean_i[bn], rstd = 1.0f / std_i[bn];
    for (int i = threadIdx.x; i < DM_ * PLEN_ * 3; i += 256) cw[i] = conv_w[i];
    const float* xp = x + (size_t)b * T_ * N_ + n;
    for (int t = threadIdx.x; t < T_; t += 256) xn[t] = (xp[(size_t)t * N_] - m) * rstd;
    __syncthreads();
    if (threadIdx.x < 8) xn[T_ + threadIdx.x] = xn[T_ - 1];
    __syncthreads();
    for (int idx = threadIdx.x; idx < L_ * DM_; idx += 256) {
        int l = idx >> 5, o = idx & 31;
        float acc = 0.f;
        #pragma unroll
        for (int t = 0; t < 3; t++) {
            int col = l + t;
            int pcol = (col == 0) ? 63 : ((col == 65) ? 0 : col - 1);
            const float* xb = &xn[pcol * 8];
            const float* cwb = &cw[o * 48 + t];
            #pragma unroll
            for (int i = 0; i < 16; i++) acc += xb[i] * cwb[i * 3];
        }
        enc[(size_t)bn * 2048 + idx] = acc;
    }
}

// ---------------- q = (enc @ wq^T + bq) * scale ----------------
__global__ __launch_bounds__(256) void k_q(const float* __restrict__ enc,
                                           const float* __restrict__ wq,
                                           const float* __restrict__ bq,
                                           float* __restrict__ qo) {
    int bn = blockIdx.x;
    __shared__ float et[2048];
    __shared__ float wqs[HF_ * DM_];
    for (int i = threadIdx.x; i < 2048; i += 256) et[i] = enc[(size_t)bn * 2048 + i];
    for (int i = threadIdx.x; i < HF_ * DM_; i += 256) wqs[i] = wq[i];
    __syncthreads();
    const float scale = 0.17677669529663687f;
    for (int idx = threadIdx.x; idx < L_ * HF_; idx += 256) {
        int l = idx >> 8, c = idx & 255;
        float acc = bq[c];
        const float* e = &et[l * 32];
        const float* w = &wqs[c * 32];
        #pragma unroll
        for (int k = 0; k < 32; k++) acc += e[k] * w[k];
        qo[(size_t)bn * L_ * HF_ + idx] = acc * scale;
    }
}

// ---------------- cvt wk,wv -> wkv_bf [512][4096] bf16 ----------------
__global__ __launch_bounds__(256) void k_cvt_wkv(const float* __restrict__ wk,
                                                 const float* __restrict__ wv,
                                                 ushort* __restrict__ out) {
    int g = blockIdx.x * 256 + threadIdx.x;
    int e = g * 8;
    const float* src = (e < HF_ * DLLM_) ? wk + e : wv + (e - HF_ * DLLM_);
    float4 x = *(const float4*)src, y = *(const float4*)(src + 4);
    uint4 w; w.x = pk(x.x, x.y); w.y = pk(x.z, x.w); w.z = pk(y.x, y.y); w.w = pk(y.z, y.w);
    *(uint4*)(out + e) = w;
}

// ---------------- GEMM1 (bf16 MFMA): E_T[512][32000] = (word_emb @ wkv^T)^T ----------------
// BM=128, BN=256, BK=32, 512 threads (8 waves 2x4, 64x64/wave).
// A: f32->bf16 reg-pack, swizzled LDS write. B: global_load_lds w/ pre-swizzled source.
// Swizzle: 16B unit of (row r, oct o) lives at u = 4r + (o ^ ((r>>1)&3)) -> 2-way (free) banks.
__global__ __launch_bounds__(512) void k_gemm1(const float* __restrict__ A,
                                               const ushort* __restrict__ Bw,
                                               ushort* __restrict__ ET) {
    __shared__ union {
        struct { ushort A[2][128 * 32]; ushort B[2][256 * 32]; } st;  // 48 KB
        ushort C[256 * 72];                                           // 36 KB epilogue
    } lds;
    const int tid = threadIdx.x;
    const int lane = tid & 63, wid = tid >> 6;
    const int wr = wid >> 2, wc = wid & 3;
    const int n0 = blockIdx.x * 256, m0 = blockIdx.y * 128;

    // A stager: thread t -> row t>>2, oct t&3; swizzled unit
    const int ar = tid >> 2, ao = tid & 3;
    const int au = (ar << 2) | (ao ^ ((ar >> 1) & 3));
    const float* aptr = A + (size_t)(m0 + ar) * DLLM_ + ao * 8;

    // B stager: units u0=tid, u1=tid+512; source octet pre-swizzled
    const int u0 = tid, rb0 = u0 >> 2, ob0 = (u0 & 3) ^ ((rb0 >> 1) & 3);
    const int u1 = tid + 512, rb1 = u1 >> 2, ob1 = (u1 & 3) ^ ((rb1 >> 1) & 3);
    const ushort* bptr0 = Bw + (size_t)(n0 + rb0) * DLLM_ + ob0 * 8;
    const ushort* bptr1 = Bw + (size_t)(n0 + rb1) * DLLM_ + ob1 * 8;

    // fragment read: row r=base+rl, swizzled oct
    const int rl = lane & 15;
    const int oc = (lane >> 4) ^ ((rl >> 1) & 3);

    f32x4 acc[4][4];
    #pragma unroll
    for (int i = 0; i < 4; i++)
        #pragma unroll
        for (int j = 0; j < 4; j++) acc[i][j] = (f32x4){0.f, 0.f, 0.f, 0.f};

    {   // prologue: stage tile 0
        gl16(bptr0, &lds.st.B[0][u0 * 8]);
        gl16(bptr1, &lds.st.B[0][u1 * 8]);
        float4 a0 = *(const float4*)aptr;
        float4 a1 = *(const float4*)(aptr + 4);
        uint4 wa; wa.x = pk(a0.x, a0.y); wa.y = pk(a0.z, a0.w); wa.z = pk(a1.x, a1.y); wa.w = pk(a1.z, a1.w);
        *(uint4*)&lds.st.A[0][au * 8] = wa;
    }
    __syncthreads();

    int cur = 0;
    constexpr int NT = DLLM_ / 32;  // 128
    for (int t = 0; t < NT; ++t) {
        const bool more = (t + 1 < NT);
        float4 a0, a1;
        if (more) {
            const int o = (t + 1) * 32;
            gl16(bptr0 + o, &lds.st.B[cur ^ 1][u0 * 8]);
            gl16(bptr1 + o, &lds.st.B[cur ^ 1][u1 * 8]);
            const float* ap = aptr + o;
            a0 = *(const float4*)ap; a1 = *(const float4*)(ap + 4);
        }
        const ushort* Ab = lds.st.A[cur];
        const ushort* Bb = lds.st.B[cur];
        bf16x8 af[4], bfr[4];
        #pragma unroll
        for (int mi = 0; mi < 4; mi++)
            af[mi] = *(const bf16x8*)&Ab[(wr * 64 + mi * 16 + rl) * 32 + oc * 8];
        #pragma unroll
        for (int ni = 0; ni < 4; ni++)
            bfr[ni] = *(const bf16x8*)&Bb[(wc * 64 + ni * 16 + rl) * 32 + oc * 8];
        #pragma unroll
        for (int mi = 0; mi < 4; mi++)
            #pragma unroll
            for (int ni = 0; ni < 4; ni++)
                acc[mi][ni] = __builtin_amdgcn_mfma_f32_16x16x32_bf16(af[mi], bfr[ni], acc[mi][ni], 0, 0, 0);
        if (more) {
            uint4 wa; wa.x = pk(a0.x, a0.y); wa.y = pk(a0.z, a0.w); wa.z = pk(a1.x, a1.y); wa.w = pk(a1.z, a1.w);
            *(uint4*)&lds.st.A[cur ^ 1][au * 8] = wa;
        }
        __syncthreads();
        cur ^= 1;
    }

    // epilogue: transpose to E_T via LDS, two rounds over wr halves
    #pragma unroll
    for (int p = 0; p < 2; p++) {
        __syncthreads();
        if (wr == p) {
            #pragma unroll
            for (int mi = 0; mi < 4; mi++)
                #pragma unroll
                for (int ni = 0; ni < 4; ni++) {
                    int nl = wc * 64 + ni * 16 + (lane & 15);
                    int ml = mi * 16 + (lane >> 4) * 4;
                    uint2 w2;
                    w2.x = pk(acc[mi][ni][0], acc[mi][ni][1]);
                    w2.y = pk(acc[mi][ni][2], acc[mi][ni][3]);
                    *(uint2*)&lds.C[nl * 72 + ml] = w2;
                }
        }
        __syncthreads();
        {
            int r = tid >> 1, half = tid & 1;
            const uint4* src = (const uint4*)&lds.C[r * 72 + half * 32];
            ushort* dst = ET + (size_t)(n0 + r) * V_ + m0 + p * 64 + half * 32;
            uint4 v0 = src[0], v1 = src[1], v2 = src[2], v3 = src[3];
            *(uint4*)(dst + 0) = v0; *(uint4*)(dst + 8) = v1;
            *(uint4*)(dst + 16) = v2; *(uint4*)(dst + 24) = v3;
        }
    }
}

// ---------------- GEMM2 (bf16 MFMA, split-K=25): Cp[kz] = map_w[:,chunk] @ E_T[:,chunk]^T ----------------
// BM=128, BN=128, BK=32, 256 threads (4 waves 2x2, 64x64/wave).
// A (f32): global_load_lds w/ pre-swizzled source into f32 LDS tile, pack on read.
//   unit(r, c) of [128 rows x 8 units-of-4-f32] lives at linear u = r*8 + (c ^ (r&7)).
// B (bf16): global_load_lds w/ pre-swizzled source (same scheme as gemm1).
__global__ __launch_bounds__(256) void k_gemm2(const float* __restrict__ A,
                                               const ushort* __restrict__ ET,
                                               float* __restrict__ Cp) {
    __shared__ float Af[2][128 * 32];    // 16 KB each
    __shared__ ushort Bs[2][128 * 32];   // 8 KB each
    const int tid = threadIdx.x, lane = tid & 63, wid = tid >> 6;
    const int wr = wid >> 1, wc = wid & 1;
    const int m0 = blockIdx.x * 128, n0 = blockIdx.y * 128, kz = blockIdx.z;
    const size_t kbase = (size_t)kz * KCH2;

    // A stager: 4 units/thread: linear unit u = i*256 + tid -> row u>>3, f32-quad c=(u&7)^(row&7)
    const float* asrc[4];
    #pragma unroll
    for (int i = 0; i < 4; i++) {
        int u = i * 256 + tid;
        int r = u >> 3, c = (u & 7) ^ (r & 7);
        int rm = m0 + r; if (rm > S_ - 1) rm = S_ - 1;  // clamp: finite garbage, discarded at C-write
        asrc[i] = A + (size_t)rm * V_ + kbase + c * 4;
    }
    // B stager: units u0=tid, u1=tid+256 (16B bf16 octets), pre-swizzled source
    const int u0 = tid, rb0 = u0 >> 2, ob0 = (u0 & 3) ^ ((rb0 >> 1) & 3);
    const int u1 = tid + 256, rb1 = u1 >> 2, ob1 = (u1 & 3) ^ ((rb1 >> 1) & 3);
    const ushort* bp0 = ET + (size_t)(n0 + rb0) * V_ + kbase + ob0 * 8;
    const ushort* bp1 = ET + (size_t)(n0 + rb1) * V_ + kbase + ob1 * 8;

    const int rl = lane & 15;
    const int oB = (lane >> 4) ^ ((rl >> 1) & 3);   // B read swizzle (16B octets)
    const int oA = lane >> 4;                        // A k-octet (swizzle applied per-row below)

    f32x4 acc[4][4];
    #pragma unroll
    for (int i = 0; i < 4; i++)
        #pragma unroll
        for (int j = 0; j < 4; j++) acc[i][j] = (f32x4){0.f, 0.f, 0.f, 0.f};

    {   // prologue: stage tile 0
        gl16(bp0, &Bs[0][u0 * 8]);
        gl16(bp1, &Bs[0][u1 * 8]);
        #pragma unroll
        for (int i = 0; i < 4; i++) gl16(asrc[i], &Af[0][(i * 256 + tid) * 4]);
    }
    __syncthreads();

    int cur = 0;
    constexpr int NT = KCH2 / 32;  // 40
    for (int t = 0; t < NT; ++t) {
        const bool more = (t + 1 < NT);
        if (more) {
            const int o = (t + 1) * 32;
            gl16(bp0 + o, &Bs[cur ^ 1][u0 * 8]);
            gl16(bp1 + o, &Bs[cur ^ 1][u1 * 8]);
            #pragma unroll
            for (int i = 0; i < 4; i++) gl16(asrc[i] + o, &Af[cur ^ 1][(i * 256 + tid) * 4]);
        }
        const float* Ab = Af[cur];
        const ushort* Bb = Bs[cur];
        bf16x8 af[4], bfr[4];
        #pragma unroll
        for (int mi = 0; mi < 4; mi++) {
            int row = wr * 64 + mi * 16 + rl;
            int s = row & 7;
            int ulo = row * 8 + ((2 * oA) ^ s);
            int uhi = row * 8 + ((2 * oA + 1) ^ s);
            f32x4 xlo = *(const f32x4*)&Ab[ulo * 4];
            f32x4 xhi = *(const f32x4*)&Ab[uhi * 4];
            uint4 w; w.x = pk(xlo[0], xlo[1]); w.y = pk(xlo[2], xlo[3]);
            w.z = pk(xhi[0], xhi[1]); w.w = pk(xhi[2], xhi[3]);
            union { uint4 u; bf16x8 b; } cv; cv.u = w;
            af[mi] = cv.b;
        }
        #pragma unroll
        for (int ni = 0; ni < 4; ni++)
            bfr[ni] = *(const bf16x8*)&Bb[(wc * 64 + ni * 16 + rl) * 32 + oB * 8];
        #pragma unroll
        for (int mi = 0; mi < 4; mi++)
            #pragma unroll
            for (int ni = 0; ni < 4; ni++)
                acc[mi][ni] = __builtin_amdgcn_mfma_f32_16x16x32_bf16(af[mi], bfr[ni], acc[mi][ni], 0, 0, 0);
        __syncthreads();
        cur ^= 1;
    }

    #pragma unroll
    for (int mi = 0; mi < 4; mi++)
        #pragma unroll
        for (int ni = 0; ni < 4; ni++)
            #pragma unroll
            for (int j = 0; j < 4; j++) {
                int m = m0 + wr * 64 + mi * 16 + (lane >> 4) * 4 + j;
                int n = n0 + wc * 64 + ni * 16 + (lane & 15);
                if (m < S_) Cp[((size_t)kz * S_ + m) * 512 + n] = acc[mi][ni][j];
            }
}

// ---------------- reduce split-K + exact bias ----------------
__global__ __launch_bounds__(256) void k_red(const float* __restrict__ Cp,
                                             const float* __restrict__ mb,
                                             const float* __restrict__ wsum,
                                             const float* __restrict__ bk,
                                             const float* __restrict__ bv,
                                             float* __restrict__ KV) {
    int idx = blockIdx.x * 256 + threadIdx.x;
    if (idx >= S_ * 512) return;
    int m = idx >> 9, n = idx & 511;
    float s = 0.f;
    #pragma unroll
    for (int z = 0; z < KSPLIT2; z++) s += Cp[(size_t)z * S_ * 512 + idx];
    float bias = (n < HF_) ? bk[n] : bv[n - HF_];
    KV[idx] = s + mb[m] * wsum[n] + bias;
}

// ---------------- flash attention per (h, bn) ----------------
constexpr int TS = 128;
__global__ __launch_bounds__(256) void k_attn(const float* __restrict__ q,
                                              const float* __restrict__ kv,
                                              float* __restrict__ rep) {
    const int h = blockIdx.x, bn = blockIdx.y;
    __shared__ float Ks[TS][36];
    __shared__ float Vs[TS][36];
    __shared__ float sm[4][64][2];
    __shared__ float buf[64][33];
    const int tid = threadIdx.x;
    const int l = tid & 63, wid = tid >> 6;

    float qreg[32];
    const float* qp = q + ((size_t)bn * L_ + l) * HF_ + h * 32;
    #pragma unroll
    for (int e = 0; e < 32; e += 4) {
        float4 v = *(const float4*)(qp + e);
        qreg[e] = v.x; qreg[e + 1] = v.y; qreg[e + 2] = v.z; qreg[e + 3] = v.w;
    }

    float m = -1e30f, sum = 0.f;
    float acc[32] = {};

    for (int s0 = 0; s0 < S_; s0 += TS) {
        for (int idx = tid; idx < TS * 8; idx += 256) {
            int r = idx >> 3, c4 = (idx & 7) * 4;
            int s = s0 + r;
            float4 kx = make_float4(0.f, 0.f, 0.f, 0.f);
            float4 vx = kx;
            if (s < S_) {
                kx = *(const float4*)(kv + (size_t)s * 512 + h * 32 + c4);
                vx = *(const float4*)(kv + (size_t)s * 512 + 256 + h * 32 + c4);
            }
            *(float4*)&Ks[r][c4] = kx;
            *(float4*)&Vs[r][c4] = vx;
        }
        __syncthreads();

        const int sbase = wid * 32;
        float sc[32];
        #pragma unroll 4
        for (int j = 0; j < 32; j++) {
            int sg = s0 + sbase + j;
            float d = 0.f;
            const float* kr = &Ks[sbase + j][0];
            #pragma unroll
            for (int e = 0; e < 32; e++) d += qreg[e] * kr[e];
            sc[j] = (sg < S_) ? d : -1e30f;
        }
        float tmax = -1e30f;
        #pragma unroll
        for (int j = 0; j < 32; j++) tmax = fmaxf(tmax, sc[j]);
        float mnew = fmaxf(m, tmax);
        float rescale = __expf(m - mnew);
        sum *= rescale;
        #pragma unroll
        for (int e = 0; e < 32; e++) acc[e] *= rescale;
        #pragma unroll 2
        for (int j = 0; j < 32; j++) {
            float p = __expf(sc[j] - mnew);
            sum += p;
            const float* vr = &Vs[sbase + j][0];
            #pragma unroll
            for (int e = 0; e < 32; e++) acc[e] += p * vr[e];
        }
        m = mnew;
        __syncthreads();
    }

    sm[wid][l][0] = m;
    sm[wid][l][1] = sum;
    __syncthreads();
    float gm = fmaxf(fmaxf(sm[0][l][0], sm[1][l][0]), fmaxf(sm[2][l][0], sm[3][l][0]));
    float gden = 0.f;
    #pragma unroll
    for (int w = 0; w < 4; w++) gden += sm[w][l][1] * __expf(sm[w][l][0] - gm);
    float f = __expf(m - gm) / gden;
    for (int i = tid; i < 64 * 33; i += 256) ((float*)buf)[i] = 0.f;
    __syncthreads();
    for (int w = 0; w < 4; w++) {
        if (wid == w) {
            #pragma unroll
            for (int e = 0; e < 32; e++) buf[l][e] += acc[e] * f;
        }
        __syncthreads();
    }
    for (int idx = tid; idx < 2048; idx += 256) {
        int ll = idx & 63, e = idx >> 6;
        rep[((size_t)bn * HF_ + h * 32 + e) * 64 + ll] = buf[ll][e];
    }
}

// ---------------- out32 = rep @ wo[0:32]^T + bo ----------------
__global__ __launch_bounds__(256) void k_out(const float* __restrict__ rep,
                                             const float* __restrict__ wo,
                                             const float* __restrict__ bo,
                                             float* __restrict__ out32) {
    const int bn = blockIdx.x;
    __shared__ float woT[HF_][32];
    const int tid = threadIdx.x;
    for (int idx = tid; idx < HF_ * 32; idx += 256) {
        int e = idx & 31, c = idx >> 5;
        woT[c][e] = wo[(size_t)e * HF_ + c];
    }
    __syncthreads();
    const int l = tid & 63, e0 = (tid >> 6) * 8;
    float acc[8];
    #pragma unroll
    for (int i = 0; i < 8; i++) acc[i] = bo[e0 + i];
    const float* rp = rep + (size_t)bn * HF_ * 64 + l;
    for (int c = 0; c < HF_; c++) {
        float rv = rp[(size_t)c * 64];
        #pragma unroll
        for (int i = 0; i < 8; i++) acc[i] += rv * woT[c][e0 + i];
    }
    float* op = out32 + ((size_t)bn * L_ + l) * 32 + e0;
    #pragma unroll
    for (int i = 0; i < 8; i++) op[i] = acc[i];
}

// ---------------- head GEMM + de-normalize ----------------
__global__ __launch_bounds__(256) void k_head(const float* __restrict__ out32,
                                              const float* __restrict__ hw,
                                              const float* __restrict__ hb,
                                              const float* __restrict__ mean_i,
                                              const float* __restrict__ std_i,
                                              float* __restrict__ out) {
    int bn = blockIdx.x, b = bn / N_, n = bn % N_;
    __shared__ float dt[2048];
    for (int i = threadIdx.x; i < 2048; i += 256) dt[i] = out32[(size_t)bn * 2048 + i];
    __syncthreads();
    float m = mean_i[bn], sd = std_i[bn];
    for (int p = threadIdx.x; p < PRED_; p += 256) {
        float acc = hb[p];
        const float* w = hw + (size_t)p * HNF_;
        for (int f = 0; f < DFF_; f++) {
            const float* wf = w + f * 64;
            #pragma unroll
            for (int ll = 0; ll < 64; ll++) acc += dt[ll * 32 + f] * wf[ll];
        }
        out[(size_t)b * PRED_ * N_ + (size_t)p * N_ + n] = acc * sd + m;
    }
}

extern "C" void kernel_launch(void* const* d_in, const int* in_sizes, int n_in,
                              void* d_out, int out_size, void* d_ws, size_t ws_size,
                              hipStream_t stream) {
    const float* x_enc   = (const float*)d_in[0];
    const float* conv_w  = (const float*)d_in[1];
    const float* word_emb= (const float*)d_in[2];
    const float* map_w   = (const float*)d_in[3];
    const float* map_b   = (const float*)d_in[4];
    const float* wq      = (const float*)d_in[5];
    const float* bq      = (const float*)d_in[6];
    const float* wk      = (const float*)d_in[7];
    const float* bk      = (const float*)d_in[8];
    const float* wv      = (const float*)d_in[9];
    const float* bv      = (const float*)d_in[10];
    const float* wo      = (const float*)d_in[11];
    const float* bo      = (const float*)d_in[12];
    const float* head_w  = (const float*)d_in[13];
    const float* head_b  = (const float*)d_in[14];

    float* ws = (float*)d_ws;
    float* mean_w = ws;                          // 256
    float* std_w  = ws + 256;                    // 256
    float* wsum_w = ws + 512;                    // 512
    float* enc_w  = ws + 1024;                   // 224*2048
    float* q_w    = enc_w + (size_t)BN_ * 2048;  // 224*16384
    float* kv_w   = q_w + (size_t)BN_ * L_ * HF_;// 1000*512
    float* o32_w  = kv_w + (size_t)S_ * 512;     // 224*2048
    float* cp_w   = o32_w + (size_t)BN_ * 2048;  // 25*1000*512 (51.2 MB)
    float* rep_w  = cp_w;                        // alias: cp dead after k_red
    ushort* et_w  = (ushort*)(cp_w + (size_t)KSPLIT2 * S_ * 512);  // 512*32000 bf16
    ushort* wkv_w = et_w + (size_t)512 * V_;                       // 512*4096 bf16

    k_stats<<<BN_, 256, 0, stream>>>(x_enc, mean_w, std_w);
    k_wsum<<<512, 256, 0, stream>>>(wk, wv, wsum_w);
    k_enc<<<BN_, 256, 0, stream>>>(x_enc, conv_w, mean_w, std_w, enc_w);
    k_q<<<BN_, 256, 0, stream>>>(enc_w, wq, bq, q_w);
    k_cvt_wkv<<<(512 * DLLM_ / 8) / 256, 256, 0, stream>>>(wk, wv, wkv_w);
    k_gemm1<<<dim3(2, V_ / 128), 512, 0, stream>>>(word_emb, wkv_w, et_w);
    k_gemm2<<<dim3(8, 4, KSPLIT2), 256, 0, stream>>>(map_w, et_w, cp_w);
    k_red<<<(S_ * 512 + 255) / 256, 256, 0, stream>>>(cp_w, map_b, wsum_w, bk, bv, kv_w);
    k_attn<<<dim3(NH_, BN_), 256, 0, stream>>>(q_w, kv_w, rep_w);
    k_out<<<BN_, 256, 0, stream>>>(rep_w, wo, bo, o32_w);
    k_head<<<BN_, 256, 0, stream>>>(o32_w, head_w, head_b, mean_w, std_w, (float*)d_out);
}

// Round 7
// 560.700 us; speedup vs baseline: 1.9997x; 1.3292x over previous
//
#include <hip/hip_runtime.h>
#include <math.h>

constexpr int B_ = 32, T_ = 512, N_ = 7, BN_ = 224;
constexpr int L_ = 64, DM_ = 32, PLEN_ = 16;
constexpr int HF_ = 256, NH_ = 8, DFF_ = 32;
constexpr int S_ = 1000, SP_ = 1024, DLLM_ = 4096, V_ = 32000;
constexpr int PRED_ = 96, HNF_ = 2048;
constexpr int KSPLIT2 = 25, KCH2 = 1280;  // GEMM2 split-K: 25 * 1280 = 32000

typedef short bf16x8 __attribute__((ext_vector_type(8)));
typedef float f32x4 __attribute__((ext_vector_type(4)));

__device__ inline ushort f2bf(float x) {
    union { float f; uint u; } v; v.f = x;
    uint r = v.u + 0x7fffu + ((v.u >> 16) & 1u);  // RNE
    return (ushort)(r >> 16);
}
__device__ inline uint pk(float a, float b) {
    return (uint)f2bf(a) | ((uint)f2bf(b) << 16);
}
__device__ inline void gl16(const void* g, void* l) {
    __builtin_amdgcn_global_load_lds(
        (const __attribute__((address_space(1))) void*)g,
        (__attribute__((address_space(3))) void*)l, 16, 0, 0);
}

// ---------------- stats: mean/stdev per (b,n) ----------------
__global__ __launch_bounds__(256) void k_stats(const float* __restrict__ x,
                                               float* __restrict__ mean_o,
                                               float* __restrict__ std_o) {
    int bn = blockIdx.x, b = bn / N_, n = bn % N_;
    const float* xp = x + (size_t)b * T_ * N_ + n;
    float s = 0.f, sq = 0.f;
    for (int t = threadIdx.x; t < T_; t += 256) { float v = xp[(size_t)t * N_]; s += v; sq += v * v; }
    for (int o = 32; o > 0; o >>= 1) { s += __shfl_down(s, o, 64); sq += __shfl_down(sq, o, 64); }
    __shared__ float rs[4], rq[4];
    int wid = threadIdx.x >> 6, lane = threadIdx.x & 63;
    if (lane == 0) { rs[wid] = s; rq[wid] = sq; }
    __syncthreads();
    if (threadIdx.x == 0) {
        float S = rs[0] + rs[1] + rs[2] + rs[3];
        float Q = rq[0] + rq[1] + rq[2] + rq[3];
        float m = S / T_;
        float var = Q / T_ - m * m;
        mean_o[bn] = m;
        std_o[bn] = sqrtf(var + 1e-5f);
    }
}

// ---------------- wsum[c] = sum_d wkv[c][d] (exact f32, for map_b folding) ----------------
__global__ __launch_bounds__(256) void k_wsum(const float* __restrict__ wk,
                                              const float* __restrict__ wv,
                                              float* __restrict__ wsum) {
    int c = blockIdx.x;
    const float* row = (c < HF_) ? wk + (size_t)c * DLLM_ : wv + (size_t)(c - HF_) * DLLM_;
    float s = 0.f;
    for (int d = threadIdx.x; d < DLLM_; d += 256) s += row[d];
    for (int o = 32; o > 0; o >>= 1) s += __shfl_down(s, o, 64);
    __shared__ float rs[4];
    int wid = threadIdx.x >> 6, lane = threadIdx.x & 63;
    if (lane == 0) rs[wid] = s;
    __syncthreads();
    if (threadIdx.x == 0) wsum[c] = rs[0] + rs[1] + rs[2] + rs[3];
}

// ---------------- normalize + patch + conv embed ----------------
__global__ __launch_bounds__(256) void k_enc(const float* __restrict__ x,
                                             const float* __restrict__ conv_w,
                                             const float* __restrict__ mean_i,
                                             const float* __restrict__ std_i,
                                             float* __restrict__ enc) {
    int bn = blockIdx.x, b = bn / N_, n = bn % N_;
    __shared__ float xn[520];
    __shared__ float cw[DM_ * PLEN_ * 3];
    float m = mean_i[bn], rstd = 1.0f / std_i[bn];
    for (int i = threadIdx.x; i < DM_ * PLEN_ * 3; i += 256) cw[i] = conv_w[i];
    const float* xp = x + (size_t)b * T_ * N_ + n;
    for (int t = threadIdx.x; t < T_; t += 256) xn[t] = (xp[(size_t)t * N_] - m) * rstd;
    __syncthreads();
    if (threadIdx.x < 8) xn[T_ + threadIdx.x] = xn[T_ - 1];
    __syncthreads();
    for (int idx = threadIdx.x; idx < L_ * DM_; idx += 256) {
        int l = idx >> 5, o = idx & 31;
        float acc = 0.f;
        #pragma unroll
        for (int t = 0; t < 3; t++) {
            int col = l + t;
            int pcol = (col == 0) ? 63 : ((col == 65) ? 0 : col - 1);
            const float* xb = &xn[pcol * 8];
            const float* cwb = &cw[o * 48 + t];
            #pragma unroll
            for (int i = 0; i < 16; i++) acc += xb[i] * cwb[i * 3];
        }
        enc[(size_t)bn * 2048 + idx] = acc;
    }
}

// ---------------- q = (enc @ wq^T + bq) * scale ----------------
__global__ __launch_bounds__(256) void k_q(const float* __restrict__ enc,
                                           const float* __restrict__ wq,
                                           const float* __restrict__ bq,
                                           float* __restrict__ qo) {
    int bn = blockIdx.x;
    __shared__ float et[2048];
    __shared__ float wqs[HF_ * DM_];
    for (int i = threadIdx.x; i < 2048; i += 256) et[i] = enc[(size_t)bn * 2048 + i];
    for (int i = threadIdx.x; i < HF_ * DM_; i += 256) wqs[i] = wq[i];
    __syncthreads();
    const float scale = 0.17677669529663687f;
    for (int idx = threadIdx.x; idx < L_ * HF_; idx += 256) {
        int l = idx >> 8, c = idx & 255;
        float acc = bq[c];
        const float* e = &et[l * 32];
        const float* w = &wqs[c * 32];
        #pragma unroll
        for (int k = 0; k < 32; k++) acc += e[k] * w[k];
        qo[(size_t)bn * L_ * HF_ + idx] = acc * scale;
    }
}

// ---------------- cvt wk,wv -> wkv_bf [512][4096] bf16 ----------------
__global__ __launch_bounds__(256) void k_cvt_wkv(const float* __restrict__ wk,
                                                 const float* __restrict__ wv,
                                                 ushort* __restrict__ out) {
    int g = blockIdx.x * 256 + threadIdx.x;
    int e = g * 8;
    const float* src = (e < HF_ * DLLM_) ? wk + e : wv + (e - HF_ * DLLM_);
    float4 x = *(const float4*)src, y = *(const float4*)(src + 4);
    uint4 w; w.x = pk(x.x, x.y); w.y = pk(x.z, x.w); w.z = pk(y.x, y.y); w.w = pk(y.z, y.w);
    *(uint4*)(out + e) = w;
}

// ---------------- GEMM1 (bf16 MFMA): E_T[512][32000] = (word_emb @ wkv^T)^T ----------------
__global__ __launch_bounds__(512) void k_gemm1(const float* __restrict__ A,
                                               const ushort* __restrict__ Bw,
                                               ushort* __restrict__ ET) {
    __shared__ union {
        struct { ushort A[2][128 * 32]; ushort B[2][256 * 32]; } st;  // 48 KB
        ushort C[256 * 72];                                           // 36 KB epilogue
    } lds;
    const int tid = threadIdx.x;
    const int lane = tid & 63, wid = tid >> 6;
    const int wr = wid >> 2, wc = wid & 3;
    const int n0 = blockIdx.x * 256, m0 = blockIdx.y * 128;

    const int ar = tid >> 2, ao = tid & 3;
    const int au = (ar << 2) | (ao ^ ((ar >> 1) & 3));
    const float* aptr = A + (size_t)(m0 + ar) * DLLM_ + ao * 8;

    const int u0 = tid, rb0 = u0 >> 2, ob0 = (u0 & 3) ^ ((rb0 >> 1) & 3);
    const int u1 = tid + 512, rb1 = u1 >> 2, ob1 = (u1 & 3) ^ ((rb1 >> 1) & 3);
    const ushort* bptr0 = Bw + (size_t)(n0 + rb0) * DLLM_ + ob0 * 8;
    const ushort* bptr1 = Bw + (size_t)(n0 + rb1) * DLLM_ + ob1 * 8;

    const int rl = lane & 15;
    const int oc = (lane >> 4) ^ ((rl >> 1) & 3);

    f32x4 acc[4][4];
    #pragma unroll
    for (int i = 0; i < 4; i++)
        #pragma unroll
        for (int j = 0; j < 4; j++) acc[i][j] = (f32x4){0.f, 0.f, 0.f, 0.f};

    {
        gl16(bptr0, &lds.st.B[0][u0 * 8]);
        gl16(bptr1, &lds.st.B[0][u1 * 8]);
        float4 a0 = *(const float4*)aptr;
        float4 a1 = *(const float4*)(aptr + 4);
        uint4 wa; wa.x = pk(a0.x, a0.y); wa.y = pk(a0.z, a0.w); wa.z = pk(a1.x, a1.y); wa.w = pk(a1.z, a1.w);
        *(uint4*)&lds.st.A[0][au * 8] = wa;
    }
    __syncthreads();

    int cur = 0;
    constexpr int NT = DLLM_ / 32;  // 128
    for (int t = 0; t < NT; ++t) {
        const bool more = (t + 1 < NT);
        float4 a0, a1;
        if (more) {
            const int o = (t + 1) * 32;
            gl16(bptr0 + o, &lds.st.B[cur ^ 1][u0 * 8]);
            gl16(bptr1 + o, &lds.st.B[cur ^ 1][u1 * 8]);
            const float* ap = aptr + o;
            a0 = *(const float4*)ap; a1 = *(const float4*)(ap + 4);
        }
        const ushort* Ab = lds.st.A[cur];
        const ushort* Bb = lds.st.B[cur];
        bf16x8 af[4], bfr[4];
        #pragma unroll
        for (int mi = 0; mi < 4; mi++)
            af[mi] = *(const bf16x8*)&Ab[(wr * 64 + mi * 16 + rl) * 32 + oc * 8];
        #pragma unroll
        for (int ni = 0; ni < 4; ni++)
            bfr[ni] = *(const bf16x8*)&Bb[(wc * 64 + ni * 16 + rl) * 32 + oc * 8];
        #pragma unroll
        for (int mi = 0; mi < 4; mi++)
            #pragma unroll
            for (int ni = 0; ni < 4; ni++)
                acc[mi][ni] = __builtin_amdgcn_mfma_f32_16x16x32_bf16(af[mi], bfr[ni], acc[mi][ni], 0, 0, 0);
        if (more) {
            uint4 wa; wa.x = pk(a0.x, a0.y); wa.y = pk(a0.z, a0.w); wa.z = pk(a1.x, a1.y); wa.w = pk(a1.z, a1.w);
            *(uint4*)&lds.st.A[cur ^ 1][au * 8] = wa;
        }
        __syncthreads();
        cur ^= 1;
    }

    #pragma unroll
    for (int p = 0; p < 2; p++) {
        __syncthreads();
        if (wr == p) {
            #pragma unroll
            for (int mi = 0; mi < 4; mi++)
                #pragma unroll
                for (int ni = 0; ni < 4; ni++) {
                    int nl = wc * 64 + ni * 16 + (lane & 15);
                    int ml = mi * 16 + (lane >> 4) * 4;
                    uint2 w2;
                    w2.x = pk(acc[mi][ni][0], acc[mi][ni][1]);
                    w2.y = pk(acc[mi][ni][2], acc[mi][ni][3]);
                    *(uint2*)&lds.C[nl * 72 + ml] = w2;
                }
        }
        __syncthreads();
        {
            int r = tid >> 1, half = tid & 1;
            const uint4* src = (const uint4*)&lds.C[r * 72 + half * 32];
            ushort* dst = ET + (size_t)(n0 + r) * V_ + m0 + p * 64 + half * 32;
            uint4 v0 = src[0], v1 = src[1], v2 = src[2], v3 = src[3];
            *(uint4*)(dst + 0) = v0; *(uint4*)(dst + 8) = v1;
            *(uint4*)(dst + 16) = v2; *(uint4*)(dst + 24) = v3;
        }
    }
}

// ---------------- GEMM2 (bf16 MFMA, split-K=25) ----------------
__global__ __launch_bounds__(256) void k_gemm2(const float* __restrict__ A,
                                               const ushort* __restrict__ ET,
                                               float* __restrict__ Cp) {
    __shared__ float Af[2][128 * 32];    // 16 KB each
    __shared__ ushort Bs[2][128 * 32];   // 8 KB each
    const int tid = threadIdx.x, lane = tid & 63, wid = tid >> 6;
    const int wr = wid >> 1, wc = wid & 1;
    const int m0 = blockIdx.x * 128, n0 = blockIdx.y * 128, kz = blockIdx.z;
    const size_t kbase = (size_t)kz * KCH2;

    const float* asrc[4];
    #pragma unroll
    for (int i = 0; i < 4; i++) {
        int u = i * 256 + tid;
        int r = u >> 3, c = (u & 7) ^ (r & 7);
        int rm = m0 + r; if (rm > S_ - 1) rm = S_ - 1;
        asrc[i] = A + (size_t)rm * V_ + kbase + c * 4;
    }
    const int u0 = tid, rb0 = u0 >> 2, ob0 = (u0 & 3) ^ ((rb0 >> 1) & 3);
    const int u1 = tid + 256, rb1 = u1 >> 2, ob1 = (u1 & 3) ^ ((rb1 >> 1) & 3);
    const ushort* bp0 = ET + (size_t)(n0 + rb0) * V_ + kbase + ob0 * 8;
    const ushort* bp1 = ET + (size_t)(n0 + rb1) * V_ + kbase + ob1 * 8;

    const int rl = lane & 15;
    const int oB = (lane >> 4) ^ ((rl >> 1) & 3);
    const int oA = lane >> 4;

    f32x4 acc[4][4];
    #pragma unroll
    for (int i = 0; i < 4; i++)
        #pragma unroll
        for (int j = 0; j < 4; j++) acc[i][j] = (f32x4){0.f, 0.f, 0.f, 0.f};

    {
        gl16(bp0, &Bs[0][u0 * 8]);
        gl16(bp1, &Bs[0][u1 * 8]);
        #pragma unroll
        for (int i = 0; i < 4; i++) gl16(asrc[i], &Af[0][(i * 256 + tid) * 4]);
    }
    __syncthreads();

    int cur = 0;
    constexpr int NT = KCH2 / 32;  // 40
    for (int t = 0; t < NT; ++t) {
        const bool more = (t + 1 < NT);
        if (more) {
            const int o = (t + 1) * 32;
            gl16(bp0 + o, &Bs[cur ^ 1][u0 * 8]);
            gl16(bp1 + o, &Bs[cur ^ 1][u1 * 8]);
            #pragma unroll
            for (int i = 0; i < 4; i++) gl16(asrc[i] + o, &Af[cur ^ 1][(i * 256 + tid) * 4]);
        }
        const float* Ab = Af[cur];
        const ushort* Bb = Bs[cur];
        bf16x8 af[4], bfr[4];
        #pragma unroll
        for (int mi = 0; mi < 4; mi++) {
            int row = wr * 64 + mi * 16 + rl;
            int s = row & 7;
            int ulo = row * 8 + ((2 * oA) ^ s);
            int uhi = row * 8 + ((2 * oA + 1) ^ s);
            f32x4 xlo = *(const f32x4*)&Ab[ulo * 4];
            f32x4 xhi = *(const f32x4*)&Ab[uhi * 4];
            uint4 w; w.x = pk(xlo[0], xlo[1]); w.y = pk(xlo[2], xlo[3]);
            w.z = pk(xhi[0], xhi[1]); w.w = pk(xhi[2], xhi[3]);
            union { uint4 u; bf16x8 b; } cv; cv.u = w;
            af[mi] = cv.b;
        }
        #pragma unroll
        for (int ni = 0; ni < 4; ni++)
            bfr[ni] = *(const bf16x8*)&Bb[(wc * 64 + ni * 16 + rl) * 32 + oB * 8];
        #pragma unroll
        for (int mi = 0; mi < 4; mi++)
            #pragma unroll
            for (int ni = 0; ni < 4; ni++)
                acc[mi][ni] = __builtin_amdgcn_mfma_f32_16x16x32_bf16(af[mi], bfr[ni], acc[mi][ni], 0, 0, 0);
        __syncthreads();
        cur ^= 1;
    }

    #pragma unroll
    for (int mi = 0; mi < 4; mi++)
        #pragma unroll
        for (int ni = 0; ni < 4; ni++)
            #pragma unroll
            for (int j = 0; j < 4; j++) {
                int m = m0 + wr * 64 + mi * 16 + (lane >> 4) * 4 + j;
                int n = n0 + wc * 64 + ni * 16 + (lane & 15);
                if (m < S_) Cp[((size_t)kz * S_ + m) * 512 + n] = acc[mi][ni][j];
            }
}

// ---------------- reduce split-K + bias -> K bf16 [1024][256] and V^T bf16 [256][1024] ----------------
__global__ __launch_bounds__(256) void k_red(const float* __restrict__ Cp,
                                             const float* __restrict__ mb,
                                             const float* __restrict__ wsum,
                                             const float* __restrict__ bk,
                                             const float* __restrict__ bv,
                                             ushort* __restrict__ Kb,
                                             ushort* __restrict__ Vt) {
    int idx = blockIdx.x * 256 + threadIdx.x;   // over SP_*512
    if (idx >= SP_ * 512) return;
    int m = idx >> 9, n = idx & 511;
    float s = 0.f;
    if (m < S_) {
        #pragma unroll
        for (int z = 0; z < KSPLIT2; z++) s += Cp[(size_t)z * S_ * 512 + (size_t)m * 512 + n];
        float bias = (n < HF_) ? bk[n] : bv[n - HF_];
        s += mb[m] * wsum[n] + bias;
    }
    ushort h = f2bf(s);
    if (n < HF_) Kb[(size_t)m * HF_ + n] = h;
    else Vt[(size_t)(n - HF_) * SP_ + m] = h;
}

// ---------------- flash attention (MFMA) per (h, bn) ----------------
// 4 waves; wave w owns q-rows 16w..16w+15. 16 s-tiles of 64 (padded to 1024, masked).
__global__ __launch_bounds__(256) void k_attn(const float* __restrict__ q,
                                              const ushort* __restrict__ Kb,
                                              const ushort* __restrict__ Vt,
                                              float* __restrict__ rep) {
    const int h = blockIdx.x, bn = blockIdx.y;
    __shared__ ushort Ks[64 * 32];     // [row][oct ^ ((row>>1)&3)], 16B units
    __shared__ ushort Vs[32 * 64];     // V^T tile: [erow][soct ^ (erow&7)]
    __shared__ float  Ps[4][16 * 64];  // per-wave P: [q][squad ^ q][s&3]
    const int tid = threadIdx.x, lane = tid & 63, w = tid >> 6;
    const int rl = lane & 15, g = lane >> 4;

    // staging source pointers (tile-invariant part); dest is linear LDS, src pre-swizzled
    const int krow = tid >> 2, koc = (tid & 3) ^ ((krow >> 1) & 3);
    const ushort* ksrc = Kb + (size_t)krow * HF_ + h * 32 + koc * 8;
    ushort* kdst = &Ks[tid * 8];
    const int verow = tid >> 3, vso = (tid & 7) ^ (verow & 7);
    const ushort* vsrc = Vt + (size_t)(h * 32 + verow) * SP_ + vso * 8;
    ushort* vdst = &Vs[tid * 8];

    // Q A-frag (scale already folded into q)
    bf16x8 qf;
    {
        const float* qp = q + ((size_t)bn * L_ + w * 16 + rl) * HF_ + h * 32 + g * 8;
        float4 x = *(const float4*)qp, y = *(const float4*)(qp + 4);
        uint4 u; u.x = pk(x.x, x.y); u.y = pk(x.z, x.w); u.z = pk(y.x, y.y); u.w = pk(y.z, y.w);
        union { uint4 u4; bf16x8 b; } cv; cv.u4 = u; qf = cv.b;
    }

    float mrow[4] = {-1e30f, -1e30f, -1e30f, -1e30f};
    float rsum[4] = {0.f, 0.f, 0.f, 0.f};
    f32x4 oacc[2] = {(f32x4){0,0,0,0}, (f32x4){0,0,0,0}};
    float* Pw = Ps[w];

    for (int t = 0; t < 16; ++t) {
        const int s0 = t * 64;
        gl16(ksrc + (size_t)s0 * HF_, kdst);
        gl16(vsrc + s0, vdst);
        __syncthreads();

        // QK^T: 4 n-frags of 16 s
        f32x4 sc[4];
        #pragma unroll
        for (int nf = 0; nf < 4; nf++) {
            const int row = nf * 16 + rl;
            bf16x8 kf = *(const bf16x8*)&Ks[(row * 4 + (g ^ ((rl >> 1) & 3))) * 8];
            sc[nf] = __builtin_amdgcn_mfma_f32_16x16x32_bf16(qf, kf, (f32x4){0, 0, 0, 0}, 0, 0, 0);
            if (s0 + row >= S_) sc[nf] = (f32x4){-1e30f, -1e30f, -1e30f, -1e30f};
        }
        // row max (tile), 16-lane reduce
        float tmax[4];
        #pragma unroll
        for (int j = 0; j < 4; j++)
            tmax[j] = fmaxf(fmaxf(sc[0][j], sc[1][j]), fmaxf(sc[2][j], sc[3][j]));
        #pragma unroll
        for (int d = 1; d < 16; d <<= 1)
            #pragma unroll
            for (int j = 0; j < 4; j++) tmax[j] = fmaxf(tmax[j], __shfl_xor(tmax[j], d, 64));
        float resc[4];
        #pragma unroll
        for (int j = 0; j < 4; j++) {
            float mn = fmaxf(mrow[j], tmax[j]);
            resc[j] = __expf(mrow[j] - mn);
            mrow[j] = mn;
            rsum[j] *= resc[j];
            oacc[0][j] *= resc[j];
            oacc[1][j] *= resc[j];
        }
        // p = exp(sc - m), store bf16-representable f32 to wave-private P
        #pragma unroll
        for (int nf = 0; nf < 4; nf++) {
            const int s = nf * 16 + rl;
            #pragma unroll
            for (int j = 0; j < 4; j++) {
                float p = __expf(sc[nf][j] - mrow[j]);
                float pf = __uint_as_float(((uint)f2bf(p)) << 16);
                rsum[j] += pf;
                const int row = 4 * g + j;
                Pw[row * 64 + (((s >> 2) ^ row) << 2) + (s & 3)] = pf;
            }
        }
        // PV: out[16q x 32e] += P[16x64] * V[64x32]
        #pragma unroll
        for (int h2 = 0; h2 < 2; h2++) {
            const int q1 = (h2 * 8 + 2 * g) ^ rl;
            const int q2 = (h2 * 8 + 2 * g + 1) ^ rl;
            f32x4 plo = *(const f32x4*)&Pw[rl * 64 + q1 * 4];
            f32x4 phi = *(const f32x4*)&Pw[rl * 64 + q2 * 4];
            uint4 pu; pu.x = pk(plo[0], plo[1]); pu.y = pk(plo[2], plo[3]);
            pu.z = pk(phi[0], phi[1]); pu.w = pk(phi[2], phi[3]);
            union { uint4 u; bf16x8 b; } cv; cv.u = pu;
            bf16x8 pa = cv.b;
            #pragma unroll
            for (int eg = 0; eg < 2; eg++) {
                const int erow = eg * 16 + rl;
                const int su = (h2 * 4 + g) ^ (erow & 7);
                bf16x8 vf = *(const bf16x8*)&Vs[erow * 64 + su * 8];
                oacc[eg] = __builtin_amdgcn_mfma_f32_16x16x32_bf16(pa, vf, oacc[eg], 0, 0, 0);
            }
        }
        __syncthreads();
    }

    // final row sums + write rep[bn][h*32+e][q]
    #pragma unroll
    for (int d = 1; d < 16; d <<= 1)
        #pragma unroll
        for (int j = 0; j < 4; j++) rsum[j] += __shfl_xor(rsum[j], d, 64);
    float inv[4];
    #pragma unroll
    for (int j = 0; j < 4; j++) inv[j] = 1.0f / rsum[j];
    #pragma unroll
    for (int eg = 0; eg < 2; eg++)
        #pragma unroll
        for (int j = 0; j < 4; j++)
            rep[((size_t)bn * HF_ + h * 32 + eg * 16 + rl) * 64 + w * 16 + 4 * g + j] =
                oacc[eg][j] * inv[j];
}

// ---------------- out32 = rep @ wo[0:32]^T + bo ----------------
__global__ __launch_bounds__(256) void k_out(const float* __restrict__ rep,
                                             const float* __restrict__ wo,
                                             const float* __restrict__ bo,
                                             float* __restrict__ out32) {
    const int bn = blockIdx.x;
    __shared__ float woT[HF_][32];
    const int tid = threadIdx.x;
    for (int idx = tid; idx < HF_ * 32; idx += 256) {
        int e = idx & 31, c = idx >> 5;
        woT[c][e] = wo[(size_t)e * HF_ + c];
    }
    __syncthreads();
    const int l = tid & 63, e0 = (tid >> 6) * 8;
    float acc[8];
    #pragma unroll
    for (int i = 0; i < 8; i++) acc[i] = bo[e0 + i];
    const float* rp = rep + (size_t)bn * HF_ * 64 + l;
    for (int c = 0; c < HF_; c++) {
        float rv = rp[(size_t)c * 64];
        #pragma unroll
        for (int i = 0; i < 8; i++) acc[i] += rv * woT[c][e0 + i];
    }
    float* op = out32 + ((size_t)bn * L_ + l) * 32 + e0;
    #pragma unroll
    for (int i = 0; i < 8; i++) op[i] = acc[i];
}

// ---------------- head GEMM + de-normalize ----------------
__global__ __launch_bounds__(256) void k_head(const float* __restrict__ out32,
                                              const float* __restrict__ hw,
                                              const float* __restrict__ hb,
                                              const float* __restrict__ mean_i,
                                              const float* __restrict__ std_i,
                                              float* __restrict__ out) {
    int bn = blockIdx.x, b = bn / N_, n = bn % N_;
    __shared__ float dt[2048];
    for (int i = threadIdx.x; i < 2048; i += 256) dt[i] = out32[(size_t)bn * 2048 + i];
    __syncthreads();
    float m = mean_i[bn], sd = std_i[bn];
    for (int p = threadIdx.x; p < PRED_; p += 256) {
        float acc = hb[p];
        const float* w = hw + (size_t)p * HNF_;
        for (int f = 0; f < DFF_; f++) {
            const float* wf = w + f * 64;
            #pragma unroll
            for (int ll = 0; ll < 64; ll++) acc += dt[ll * 32 + f] * wf[ll];
        }
        out[(size_t)b * PRED_ * N_ + (size_t)p * N_ + n] = acc * sd + m;
    }
}

extern "C" void kernel_launch(void* const* d_in, const int* in_sizes, int n_in,
                              void* d_out, int out_size, void* d_ws, size_t ws_size,
                              hipStream_t stream) {
    const float* x_enc   = (const float*)d_in[0];
    const float* conv_w  = (const float*)d_in[1];
    const float* word_emb= (const float*)d_in[2];
    const float* map_w   = (const float*)d_in[3];
    const float* map_b   = (const float*)d_in[4];
    const float* wq      = (const float*)d_in[5];
    const float* bq      = (const float*)d_in[6];
    const float* wk      = (const float*)d_in[7];
    const float* bk      = (const float*)d_in[8];
    const float* wv      = (const float*)d_in[9];
    const float* bv      = (const float*)d_in[10];
    const float* wo      = (const float*)d_in[11];
    const float* bo      = (const float*)d_in[12];
    const float* head_w  = (const float*)d_in[13];
    const float* head_b  = (const float*)d_in[14];

    float* ws = (float*)d_ws;
    float* mean_w = ws;                          // 256
    float* std_w  = ws + 256;                    // 256
    float* wsum_w = ws + 512;                    // 512
    float* enc_w  = ws + 1024;                   // 224*2048
    float* q_w    = enc_w + (size_t)BN_ * 2048;  // 224*16384
    float* kv_w   = q_w + (size_t)BN_ * L_ * HF_;// 2 MB region, reused for bf16 K/V^T
    float* o32_w  = kv_w + (size_t)S_ * 512;     // 224*2048
    float* cp_w   = o32_w + (size_t)BN_ * 2048;  // 25*1000*512 (51.2 MB)
    float* rep_w  = cp_w;                        // alias: cp dead after k_red
    ushort* et_w  = (ushort*)(cp_w + (size_t)KSPLIT2 * S_ * 512);  // 512*32000 bf16
    ushort* wkv_w = et_w + (size_t)512 * V_;                       // 512*4096 bf16
    ushort* kb_w  = (ushort*)kv_w;               // [1024][256] bf16 (512 KB)
    ushort* vt_w  = kb_w + (size_t)SP_ * HF_;    // [256][1024] bf16 (512 KB)

    k_stats<<<BN_, 256, 0, stream>>>(x_enc, mean_w, std_w);
    k_wsum<<<512, 256, 0, stream>>>(wk, wv, wsum_w);
    k_enc<<<BN_, 256, 0, stream>>>(x_enc, conv_w, mean_w, std_w, enc_w);
    k_q<<<BN_, 256, 0, stream>>>(enc_w, wq, bq, q_w);
    k_cvt_wkv<<<(512 * DLLM_ / 8) / 256, 256, 0, stream>>>(wk, wv, wkv_w);
    k_gemm1<<<dim3(2, V_ / 128), 512, 0, stream>>>(word_emb, wkv_w, et_w);
    k_gemm2<<<dim3(8, 4, KSPLIT2), 256, 0, stream>>>(map_w, et_w, cp_w);
    k_red<<<(SP_ * 512) / 256, 256, 0, stream>>>(cp_w, map_b, wsum_w, bk, bv, kb_w, vt_w);
    k_attn<<<dim3(NH_, BN_), 256, 0, stream>>>(q_w, kb_w, vt_w, rep_w);
    k_out<<<BN_, 256, 0, stream>>>(rep_w, wo, bo, o32_w);
    k_head<<<BN_, 256, 0, stream>>>(o32_w, head_w, head_b, mean_w, std_w, (float*)d_out);
}

// Round 8
// 532.254 us; speedup vs baseline: 2.1066x; 1.0534x over previous
//
#include <hip/hip_runtime.h>
#include <math.h>

constexpr int B_ = 32, T_ = 512, N_ = 7, BN_ = 224;
constexpr int L_ = 64, DM_ = 32, PLEN_ = 16;
constexpr int HF_ = 256, NH_ = 8, DFF_ = 32;
constexpr int S_ = 1000, SP_ = 1024, DLLM_ = 4096, V_ = 32000;
constexpr int PRED_ = 96, HNF_ = 2048;
constexpr int KSPLIT2 = 25, KCH2 = 1280;  // GEMM2 split-K: 25 * 1280 = 32000

typedef short bf16x8 __attribute__((ext_vector_type(8)));
typedef float f32x4 __attribute__((ext_vector_type(4)));

__device__ inline ushort f2bf(float x) {
    union { float f; uint u; } v; v.f = x;
    uint r = v.u + 0x7fffu + ((v.u >> 16) & 1u);  // RNE
    return (ushort)(r >> 16);
}
__device__ inline uint pk(float a, float b) {
    return (uint)f2bf(a) | ((uint)f2bf(b) << 16);
}
__device__ inline void gl16(const void* g, void* l) {
    __builtin_amdgcn_global_load_lds(
        (const __attribute__((address_space(1))) void*)g,
        (__attribute__((address_space(3))) void*)l, 16, 0, 0);
}

// ---------------- stats: mean/stdev per (b,n) ----------------
__global__ __launch_bounds__(256) void k_stats(const float* __restrict__ x,
                                               float* __restrict__ mean_o,
                                               float* __restrict__ std_o) {
    int bn = blockIdx.x, b = bn / N_, n = bn % N_;
    const float* xp = x + (size_t)b * T_ * N_ + n;
    float s = 0.f, sq = 0.f;
    for (int t = threadIdx.x; t < T_; t += 256) { float v = xp[(size_t)t * N_]; s += v; sq += v * v; }
    for (int o = 32; o > 0; o >>= 1) { s += __shfl_down(s, o, 64); sq += __shfl_down(sq, o, 64); }
    __shared__ float rs[4], rq[4];
    int wid = threadIdx.x >> 6, lane = threadIdx.x & 63;
    if (lane == 0) { rs[wid] = s; rq[wid] = sq; }
    __syncthreads();
    if (threadIdx.x == 0) {
        float S = rs[0] + rs[1] + rs[2] + rs[3];
        float Q = rq[0] + rq[1] + rq[2] + rq[3];
        float m = S / T_;
        float var = Q / T_ - m * m;
        mean_o[bn] = m;
        std_o[bn] = sqrtf(var + 1e-5f);
    }
}

// ---------------- wsum[c] = sum_d wkv[c][d] (exact f32, for map_b folding) ----------------
__global__ __launch_bounds__(256) void k_wsum(const float* __restrict__ wk,
                                              const float* __restrict__ wv,
                                              float* __restrict__ wsum) {
    int c = blockIdx.x;
    const float* row = (c < HF_) ? wk + (size_t)c * DLLM_ : wv + (size_t)(c - HF_) * DLLM_;
    float s = 0.f;
    for (int d = threadIdx.x; d < DLLM_; d += 256) s += row[d];
    for (int o = 32; o > 0; o >>= 1) s += __shfl_down(s, o, 64);
    __shared__ float rs[4];
    int wid = threadIdx.x >> 6, lane = threadIdx.x & 63;
    if (lane == 0) rs[wid] = s;
    __syncthreads();
    if (threadIdx.x == 0) wsum[c] = rs[0] + rs[1] + rs[2] + rs[3];
}

// ---------------- normalize + patch + conv embed ----------------
__global__ __launch_bounds__(256) void k_enc(const float* __restrict__ x,
                                             const float* __restrict__ conv_w,
                                             const float* __restrict__ mean_i,
                                             const float* __restrict__ std_i,
                                             float* __restrict__ enc) {
    int bn = blockIdx.x, b = bn / N_, n = bn % N_;
    __shared__ float xn[520];
    __shared__ float cw[DM_ * PLEN_ * 3];
    float m = mean_i[bn], rstd = 1.0f / std_i[bn];
    for (int i = threadIdx.x; i < DM_ * PLEN_ * 3; i += 256) cw[i] = conv_w[i];
    const float* xp = x + (size_t)b * T_ * N_ + n;
    for (int t = threadIdx.x; t < T_; t += 256) xn[t] = (xp[(size_t)t * N_] - m) * rstd;
    __syncthreads();
    if (threadIdx.x < 8) xn[T_ + threadIdx.x] = xn[T_ - 1];
    __syncthreads();
    for (int idx = threadIdx.x; idx < L_ * DM_; idx += 256) {
        int l = idx >> 5, o = idx & 31;
        float acc = 0.f;
        #pragma unroll
        for (int t = 0; t < 3; t++) {
            int col = l + t;
            int pcol = (col == 0) ? 63 : ((col == 65) ? 0 : col - 1);
            const float* xb = &xn[pcol * 8];
            const float* cwb = &cw[o * 48 + t];
            #pragma unroll
            for (int i = 0; i < 16; i++) acc += xb[i] * cwb[i * 3];
        }
        enc[(size_t)bn * 2048 + idx] = acc;
    }
}

// ---------------- q = (enc @ wq^T + bq) * scale ----------------
__global__ __launch_bounds__(256) void k_q(const float* __restrict__ enc,
                                           const float* __restrict__ wq,
                                           const float* __restrict__ bq,
                                           float* __restrict__ qo) {
    int bn = blockIdx.x;
    __shared__ float et[2048];
    __shared__ float wqs[HF_ * DM_];
    for (int i = threadIdx.x; i < 2048; i += 256) et[i] = enc[(size_t)bn * 2048 + i];
    for (int i = threadIdx.x; i < HF_ * DM_; i += 256) wqs[i] = wq[i];
    __syncthreads();
    const float scale = 0.17677669529663687f;
    for (int idx = threadIdx.x; idx < L_ * HF_; idx += 256) {
        int l = idx >> 8, c = idx & 255;
        float acc = bq[c];
        const float* e = &et[l * 32];
        const float* w = &wqs[c * 32];
        #pragma unroll
        for (int k = 0; k < 32; k++) acc += e[k] * w[k];
        qo[(size_t)bn * L_ * HF_ + idx] = acc * scale;
    }
}

// ---------------- cvt wk,wv -> wkv_bf [512][4096] bf16 ----------------
__global__ __launch_bounds__(256) void k_cvt_wkv(const float* __restrict__ wk,
                                                 const float* __restrict__ wv,
                                                 ushort* __restrict__ out) {
    int g = blockIdx.x * 256 + threadIdx.x;
    int e = g * 8;
    const float* src = (e < HF_ * DLLM_) ? wk + e : wv + (e - HF_ * DLLM_);
    float4 x = *(const float4*)src, y = *(const float4*)(src + 4);
    uint4 w; w.x = pk(x.x, x.y); w.y = pk(x.z, x.w); w.z = pk(y.x, y.y); w.w = pk(y.z, y.w);
    *(uint4*)(out + e) = w;
}

// ---------------- GEMM1 (bf16 MFMA, counted-vmcnt pipeline) ----------------
// E_T[512][32000] = (word_emb @ wkv^T)^T. BM=128, BN=256, BK=32, 512 thr (8 waves 2x4).
// A: f32 tile via gl16 (swizzle u=r*8+(c^(r&7))), pack f32->bf16 on read.
// B: bf16 via gl16 (swizzle oct^((row>>1)&3)). 4 gl16/wave/tile -> vmcnt(4).
__global__ __launch_bounds__(512) void k_gemm1(const float* __restrict__ A,
                                               const ushort* __restrict__ Bw,
                                               ushort* __restrict__ ET) {
    __shared__ union {
        struct { float Af[2][128 * 32]; ushort Bs[2][256 * 32]; } st;  // 64 KB
        ushort C[256 * 72];                                            // 36 KB epilogue
    } lds;
    const int tid = threadIdx.x;
    const int lane = tid & 63, wid = tid >> 6;
    const int wr = wid >> 2, wc = wid & 3;
    const int n0 = blockIdx.x * 256, m0 = blockIdx.y * 128;

    // A stager: units u = tid, tid+512 -> row u>>3, f32-quad (u&7)^(row&7)
    const int arw = tid >> 3, acq = (tid & 7) ^ ((tid >> 3) & 7);
    const float* asrc0 = A + (size_t)(m0 + arw) * DLLM_ + acq * 4;
    const float* asrc1 = asrc0 + (size_t)64 * DLLM_;

    // B stager: units u0=tid, u1=tid+512; source octet pre-swizzled
    const int u0 = tid, rb0 = u0 >> 2, ob0 = (u0 & 3) ^ ((rb0 >> 1) & 3);
    const int u1 = tid + 512, rb1 = u1 >> 2, ob1 = (u1 & 3) ^ ((rb1 >> 1) & 3);
    const ushort* bptr0 = Bw + (size_t)(n0 + rb0) * DLLM_ + ob0 * 8;
    const ushort* bptr1 = Bw + (size_t)(n0 + rb1) * DLLM_ + ob1 * 8;

    const int rl = lane & 15, g = lane >> 4;
    const int oc = g ^ ((rl >> 1) & 3);   // B read swizzle

    f32x4 acc[4][4];
    #pragma unroll
    for (int i = 0; i < 4; i++)
        #pragma unroll
        for (int j = 0; j < 4; j++) acc[i][j] = (f32x4){0.f, 0.f, 0.f, 0.f};

    // prologue: stage tile 0, full drain once
    gl16(asrc0, &lds.st.Af[0][tid * 4]);
    gl16(asrc1, &lds.st.Af[0][(tid + 512) * 4]);
    gl16(bptr0, &lds.st.Bs[0][u0 * 8]);
    gl16(bptr1, &lds.st.Bs[0][u1 * 8]);
    __syncthreads();

    int cur = 0;
    constexpr int NT = DLLM_ / 32;  // 128
    for (int t = 0; t < NT; ++t) {
        if (t + 1 < NT) {
            const int o = (t + 1) * 32;
            gl16(asrc0 + o, &lds.st.Af[cur ^ 1][tid * 4]);
            gl16(asrc1 + o, &lds.st.Af[cur ^ 1][(tid + 512) * 4]);
            gl16(bptr0 + o, &lds.st.Bs[cur ^ 1][u0 * 8]);
            gl16(bptr1 + o, &lds.st.Bs[cur ^ 1][u1 * 8]);
            asm volatile("s_waitcnt vmcnt(4)" ::: "memory");  // tile t landed; t+1 in flight
        } else {
            asm volatile("s_waitcnt vmcnt(0)" ::: "memory");
        }
        __builtin_amdgcn_s_barrier();
        asm volatile("" ::: "memory");   // keep ds_reads below the barrier
        const float* Ab = lds.st.Af[cur];
        const ushort* Bb = lds.st.Bs[cur];
        bf16x8 af[4], bfr[4];
        #pragma unroll
        for (int mi = 0; mi < 4; mi++) {
            int row = wr * 64 + mi * 16 + rl;
            int s = row & 7;
            int ulo = row * 8 + ((2 * g) ^ s);
            int uhi = row * 8 + ((2 * g + 1) ^ s);
            f32x4 xlo = *(const f32x4*)&Ab[ulo * 4];
            f32x4 xhi = *(const f32x4*)&Ab[uhi * 4];
            uint4 w; w.x = pk(xlo[0], xlo[1]); w.y = pk(xlo[2], xlo[3]);
            w.z = pk(xhi[0], xhi[1]); w.w = pk(xhi[2], xhi[3]);
            union { uint4 u; bf16x8 b; } cv; cv.u = w;
            af[mi] = cv.b;
        }
        #pragma unroll
        for (int ni = 0; ni < 4; ni++)
            bfr[ni] = *(const bf16x8*)&Bb[(wc * 64 + ni * 16 + rl) * 32 + oc * 8];
        __builtin_amdgcn_s_setprio(1);
        #pragma unroll
        for (int mi = 0; mi < 4; mi++)
            #pragma unroll
            for (int ni = 0; ni < 4; ni++)
                acc[mi][ni] = __builtin_amdgcn_mfma_f32_16x16x32_bf16(af[mi], bfr[ni], acc[mi][ni], 0, 0, 0);
        __builtin_amdgcn_s_setprio(0);
        asm volatile("s_waitcnt lgkmcnt(0)" ::: "memory");  // reads retired before buf reuse
        __builtin_amdgcn_s_barrier();
        cur ^= 1;
    }

    // epilogue: transpose to E_T via LDS (full-drain barriers), two rounds over wr halves
    #pragma unroll
    for (int p = 0; p < 2; p++) {
        __syncthreads();
        if (wr == p) {
            #pragma unroll
            for (int mi = 0; mi < 4; mi++)
                #pragma unroll
                for (int ni = 0; ni < 4; ni++) {
                    int nl = wc * 64 + ni * 16 + (lane & 15);
                    int ml = mi * 16 + (lane >> 4) * 4;
                    uint2 w2;
                    w2.x = pk(acc[mi][ni][0], acc[mi][ni][1]);
                    w2.y = pk(acc[mi][ni][2], acc[mi][ni][3]);
                    *(uint2*)&lds.C[nl * 72 + ml] = w2;
                }
        }
        __syncthreads();
        {
            int r = tid >> 1, half = tid & 1;
            const uint4* src = (const uint4*)&lds.C[r * 72 + half * 32];
            ushort* dst = ET + (size_t)(n0 + r) * V_ + m0 + p * 64 + half * 32;
            uint4 v0 = src[0], v1 = src[1], v2 = src[2], v3 = src[3];
            *(uint4*)(dst + 0) = v0; *(uint4*)(dst + 8) = v1;
            *(uint4*)(dst + 16) = v2; *(uint4*)(dst + 24) = v3;
        }
    }
}

// ---------------- GEMM2 (bf16 MFMA, split-K=25, counted-vmcnt pipeline) ----------------
// BM=128, BN=128, BK=32, 256 thr (4 waves 2x2). 6 gl16/wave/tile -> vmcnt(6).
__global__ __launch_bounds__(256) void k_gemm2(const float* __restrict__ A,
                                               const ushort* __restrict__ ET,
                                               float* __restrict__ Cp) {
    __shared__ float Af[2][128 * 32];    // 16 KB each
    __shared__ ushort Bs[2][128 * 32];   // 8 KB each
    const int tid = threadIdx.x, lane = tid & 63, wid = tid >> 6;
    const int wr = wid >> 1, wc = wid & 1;
    const int m0 = blockIdx.x * 128, n0 = blockIdx.y * 128, kz = blockIdx.z;
    const size_t kbase = (size_t)kz * KCH2;

    const float* asrc[4];
    #pragma unroll
    for (int i = 0; i < 4; i++) {
        int u = i * 256 + tid;
        int r = u >> 3, c = (u & 7) ^ (r & 7);
        int rm = m0 + r; if (rm > S_ - 1) rm = S_ - 1;   // clamp: discarded at C-write
        asrc[i] = A + (size_t)rm * V_ + kbase + c * 4;
    }
    const int u0 = tid, rb0 = u0 >> 2, ob0 = (u0 & 3) ^ ((rb0 >> 1) & 3);
    const int u1 = tid + 256, rb1 = u1 >> 2, ob1 = (u1 & 3) ^ ((rb1 >> 1) & 3);
    const ushort* bp0 = ET + (size_t)(n0 + rb0) * V_ + kbase + ob0 * 8;
    const ushort* bp1 = ET + (size_t)(n0 + rb1) * V_ + kbase + ob1 * 8;

    const int rl = lane & 15, g = lane >> 4;
    const int oB = g ^ ((rl >> 1) & 3);

    f32x4 acc[4][4];
    #pragma unroll
    for (int i = 0; i < 4; i++)
        #pragma unroll
        for (int j = 0; j < 4; j++) acc[i][j] = (f32x4){0.f, 0.f, 0.f, 0.f};

    // prologue
    gl16(bp0, &Bs[0][u0 * 8]);
    gl16(bp1, &Bs[0][u1 * 8]);
    #pragma unroll
    for (int i = 0; i < 4; i++) gl16(asrc[i], &Af[0][(i * 256 + tid) * 4]);
    __syncthreads();

    int cur = 0;
    constexpr int NT = KCH2 / 32;  // 40
    for (int t = 0; t < NT; ++t) {
        if (t + 1 < NT) {
            const int o = (t + 1) * 32;
            gl16(bp0 + o, &Bs[cur ^ 1][u0 * 8]);
            gl16(bp1 + o, &Bs[cur ^ 1][u1 * 8]);
            #pragma unroll
            for (int i = 0; i < 4; i++) gl16(asrc[i] + o, &Af[cur ^ 1][(i * 256 + tid) * 4]);
            asm volatile("s_waitcnt vmcnt(6)" ::: "memory");
        } else {
            asm volatile("s_waitcnt vmcnt(0)" ::: "memory");
        }
        __builtin_amdgcn_s_barrier();
        asm volatile("" ::: "memory");
        const float* Ab = Af[cur];
        const ushort* Bb = Bs[cur];
        bf16x8 af[4], bfr[4];
        #pragma unroll
        for (int mi = 0; mi < 4; mi++) {
            int row = wr * 64 + mi * 16 + rl;
            int s = row & 7;
            int ulo = row * 8 + ((2 * g) ^ s);
            int uhi = row * 8 + ((2 * g + 1) ^ s);
            f32x4 xlo = *(const f32x4*)&Ab[ulo * 4];
            f32x4 xhi = *(const f32x4*)&Ab[uhi * 4];
            uint4 w; w.x = pk(xlo[0], xlo[1]); w.y = pk(xlo[2], xlo[3]);
            w.z = pk(xhi[0], xhi[1]); w.w = pk(xhi[2], xhi[3]);
            union { uint4 u; bf16x8 b; } cv; cv.u = w;
            af[mi] = cv.b;
        }
        #pragma unroll
        for (int ni = 0; ni < 4; ni++)
            bfr[ni] = *(const bf16x8*)&Bb[(wc * 64 + ni * 16 + rl) * 32 + oB * 8];
        __builtin_amdgcn_s_setprio(1);
        #pragma unroll
        for (int mi = 0; mi < 4; mi++)
            #pragma unroll
            for (int ni = 0; ni < 4; ni++)
                acc[mi][ni] = __builtin_amdgcn_mfma_f32_16x16x32_bf16(af[mi], bfr[ni], acc[mi][ni], 0, 0, 0);
        __builtin_amdgcn_s_setprio(0);
        asm volatile("s_waitcnt lgkmcnt(0)" ::: "memory");
        __builtin_amdgcn_s_barrier();
        cur ^= 1;
    }

    #pragma unroll
    for (int mi = 0; mi < 4; mi++)
        #pragma unroll
        for (int ni = 0; ni < 4; ni++)
            #pragma unroll
            for (int j = 0; j < 4; j++) {
                int m = m0 + wr * 64 + mi * 16 + (lane >> 4) * 4 + j;
                int n = n0 + wc * 64 + ni * 16 + (lane & 15);
                if (m < S_) Cp[((size_t)kz * S_ + m) * 512 + n] = acc[mi][ni][j];
            }
}

// ---------------- reduce split-K + bias -> K bf16 [1024][256] and V^T bf16 [256][1024] ----------------
__global__ __launch_bounds__(256) void k_red(const float* __restrict__ Cp,
                                             const float* __restrict__ mb,
                                             const float* __restrict__ wsum,
                                             const float* __restrict__ bk,
                                             const float* __restrict__ bv,
                                             ushort* __restrict__ Kb,
                                             ushort* __restrict__ Vt) {
    int idx = blockIdx.x * 256 + threadIdx.x;   // over SP_*512
    if (idx >= SP_ * 512) return;
    int m = idx >> 9, n = idx & 511;
    float s = 0.f;
    if (m < S_) {
        #pragma unroll
        for (int z = 0; z < KSPLIT2; z++) s += Cp[(size_t)z * S_ * 512 + (size_t)m * 512 + n];
        float bias = (n < HF_) ? bk[n] : bv[n - HF_];
        s += mb[m] * wsum[n] + bias;
    }
    ushort h = f2bf(s);
    if (n < HF_) Kb[(size_t)m * HF_ + n] = h;
    else Vt[(size_t)(n - HF_) * SP_ + m] = h;
}

// ---------------- flash attention (MFMA) per (h, bn) ----------------
__global__ __launch_bounds__(256) void k_attn(const float* __restrict__ q,
                                              const ushort* __restrict__ Kb,
                                              const ushort* __restrict__ Vt,
                                              float* __restrict__ rep) {
    const int h = blockIdx.x, bn = blockIdx.y;
    __shared__ ushort Ks[64 * 32];     // [row][oct ^ ((row>>1)&3)], 16B units
    __shared__ ushort Vs[32 * 64];     // V^T tile: [erow][soct ^ (erow&7)]
    __shared__ float  Ps[4][16 * 64];  // per-wave P: [q][squad ^ q][s&3]
    const int tid = threadIdx.x, lane = tid & 63, w = tid >> 6;
    const int rl = lane & 15, g = lane >> 4;

    const int krow = tid >> 2, koc = (tid & 3) ^ ((krow >> 1) & 3);
    const ushort* ksrc = Kb + (size_t)krow * HF_ + h * 32 + koc * 8;
    ushort* kdst = &Ks[tid * 8];
    const int verow = tid >> 3, vso = (tid & 7) ^ (verow & 7);
    const ushort* vsrc = Vt + (size_t)(h * 32 + verow) * SP_ + vso * 8;
    ushort* vdst = &Vs[tid * 8];

    bf16x8 qf;
    {
        const float* qp = q + ((size_t)bn * L_ + w * 16 + rl) * HF_ + h * 32 + g * 8;
        float4 x = *(const float4*)qp, y = *(const float4*)(qp + 4);
        uint4 u; u.x = pk(x.x, x.y); u.y = pk(x.z, x.w); u.z = pk(y.x, y.y); u.w = pk(y.z, y.w);
        union { uint4 u4; bf16x8 b; } cv; cv.u4 = u; qf = cv.b;
    }

    float mrow[4] = {-1e30f, -1e30f, -1e30f, -1e30f};
    float rsum[4] = {0.f, 0.f, 0.f, 0.f};
    f32x4 oacc[2] = {(f32x4){0,0,0,0}, (f32x4){0,0,0,0}};
    float* Pw = Ps[w];

    for (int t = 0; t < 16; ++t) {
        const int s0 = t * 64;
        gl16(ksrc + (size_t)s0 * HF_, kdst);
        gl16(vsrc + s0, vdst);
        __syncthreads();

        f32x4 sc[4];
        __builtin_amdgcn_s_setprio(1);
        #pragma unroll
        for (int nf = 0; nf < 4; nf++) {
            const int row = nf * 16 + rl;
            bf16x8 kf = *(const bf16x8*)&Ks[(row * 4 + (g ^ ((rl >> 1) & 3))) * 8];
            sc[nf] = __builtin_amdgcn_mfma_f32_16x16x32_bf16(qf, kf, (f32x4){0, 0, 0, 0}, 0, 0, 0);
            if (s0 + row >= S_) sc[nf] = (f32x4){-1e30f, -1e30f, -1e30f, -1e30f};
        }
        __builtin_amdgcn_s_setprio(0);
        float tmax[4];
        #pragma unroll
        for (int j = 0; j < 4; j++)
            tmax[j] = fmaxf(fmaxf(sc[0][j], sc[1][j]), fmaxf(sc[2][j], sc[3][j]));
        #pragma unroll
        for (int d = 1; d < 16; d <<= 1)
            #pragma unroll
            for (int j = 0; j < 4; j++) tmax[j] = fmaxf(tmax[j], __shfl_xor(tmax[j], d, 64));
        float resc[4];
        #pragma unroll
        for (int j = 0; j < 4; j++) {
            float mn = fmaxf(mrow[j], tmax[j]);
            resc[j] = __expf(mrow[j] - mn);
            mrow[j] = mn;
            rsum[j] *= resc[j];
            oacc[0][j] *= resc[j];
            oacc[1][j] *= resc[j];
        }
        #pragma unroll
        for (int nf = 0; nf < 4; nf++) {
            const int s = nf * 16 + rl;
            #pragma unroll
            for (int j = 0; j < 4; j++) {
                float p = __expf(sc[nf][j] - mrow[j]);
                float pf = __uint_as_float(((uint)f2bf(p)) << 16);
                rsum[j] += pf;
                const int row = 4 * g + j;
                Pw[row * 64 + (((s >> 2) ^ row) << 2) + (s & 3)] = pf;
            }
        }
        __builtin_amdgcn_s_setprio(1);
        #pragma unroll
        for (int h2 = 0; h2 < 2; h2++) {
            const int q1 = (h2 * 8 + 2 * g) ^ rl;
            const int q2 = (h2 * 8 + 2 * g + 1) ^ rl;
            f32x4 plo = *(const f32x4*)&Pw[rl * 64 + q1 * 4];
            f32x4 phi = *(const f32x4*)&Pw[rl * 64 + q2 * 4];
            uint4 pu; pu.x = pk(plo[0], plo[1]); pu.y = pk(plo[2], plo[3]);
            pu.z = pk(phi[0], phi[1]); pu.w = pk(phi[2], phi[3]);
            union { uint4 u; bf16x8 b; } cv; cv.u = pu;
            bf16x8 pa = cv.b;
            #pragma unroll
            for (int eg = 0; eg < 2; eg++) {
                const int erow = eg * 16 + rl;
                const int su = (h2 * 4 + g) ^ (erow & 7);
                bf16x8 vf = *(const bf16x8*)&Vs[erow * 64 + su * 8];
                oacc[eg] = __builtin_amdgcn_mfma_f32_16x16x32_bf16(pa, vf, oacc[eg], 0, 0, 0);
            }
        }
        __builtin_amdgcn_s_setprio(0);
        __syncthreads();
    }

    #pragma unroll
    for (int d = 1; d < 16; d <<= 1)
        #pragma unroll
        for (int j = 0; j < 4; j++) rsum[j] += __shfl_xor(rsum[j], d, 64);
    float inv[4];
    #pragma unroll
    for (int j = 0; j < 4; j++) inv[j] = 1.0f / rsum[j];
    #pragma unroll
    for (int eg = 0; eg < 2; eg++)
        #pragma unroll
        for (int j = 0; j < 4; j++)
            rep[((size_t)bn * HF_ + h * 32 + eg * 16 + rl) * 64 + w * 16 + 4 * g + j] =
                oacc[eg][j] * inv[j];
}

// ---------------- out32 = rep @ wo[0:32]^T + bo ----------------
__global__ __launch_bounds__(256) void k_out(const float* __restrict__ rep,
                                             const float* __restrict__ wo,
                                             const float* __restrict__ bo,
                                             float* __restrict__ out32) {
    const int bn = blockIdx.x;
    __shared__ float woT[HF_][32];
    const int tid = threadIdx.x;
    for (int idx = tid; idx < HF_ * 32; idx += 256) {
        int e = idx & 31, c = idx >> 5;
        woT[c][e] = wo[(size_t)e * HF_ + c];
    }
    __syncthreads();
    const int l = tid & 63, e0 = (tid >> 6) * 8;
    float acc[8];
    #pragma unroll
    for (int i = 0; i < 8; i++) acc[i] = bo[e0 + i];
    const float* rp = rep + (size_t)bn * HF_ * 64 + l;
    for (int c = 0; c < HF_; c++) {
        float rv = rp[(size_t)c * 64];
        #pragma unroll
        for (int i = 0; i < 8; i++) acc[i] += rv * woT[c][e0 + i];
    }
    float* op = out32 + ((size_t)bn * L_ + l) * 32 + e0;
    #pragma unroll
    for (int i = 0; i < 8; i++) op[i] = acc[i];
}

// ---------------- head GEMM + de-normalize ----------------
__global__ __launch_bounds__(256) void k_head(const float* __restrict__ out32,
                                              const float* __restrict__ hw,
                                              const float* __restrict__ hb,
                                              const float* __restrict__ mean_i,
                                              const float* __restrict__ std_i,
                                              float* __restrict__ out) {
    int bn = blockIdx.x, b = bn / N_, n = bn % N_;
    __shared__ float dt[2048];
    for (int i = threadIdx.x; i < 2048; i += 256) dt[i] = out32[(size_t)bn * 2048 + i];
    __syncthreads();
    float m = mean_i[bn], sd = std_i[bn];
    for (int p = threadIdx.x; p < PRED_; p += 256) {
        float acc = hb[p];
        const float* w = hw + (size_t)p * HNF_;
        for (int f = 0; f < DFF_; f++) {
            const float* wf = w + f * 64;
            #pragma unroll
            for (int ll = 0; ll < 64; ll++) acc += dt[ll * 32 + f] * wf[ll];
        }
        out[(size_t)b * PRED_ * N_ + (size_t)p * N_ + n] = acc * sd + m;
    }
}

extern "C" void kernel_launch(void* const* d_in, const int* in_sizes, int n_in,
                              void* d_out, int out_size, void* d_ws, size_t ws_size,
                              hipStream_t stream) {
    const float* x_enc   = (const float*)d_in[0];
    const float* conv_w  = (const float*)d_in[1];
    const float* word_emb= (const float*)d_in[2];
    const float* map_w   = (const float*)d_in[3];
    const float* map_b   = (const float*)d_in[4];
    const float* wq      = (const float*)d_in[5];
    const float* bq      = (const float*)d_in[6];
    const float* wk      = (const float*)d_in[7];
    const float* bk      = (const float*)d_in[8];
    const float* wv      = (const float*)d_in[9];
    const float* bv      = (const float*)d_in[10];
    const float* wo      = (const float*)d_in[11];
    const float* bo      = (const float*)d_in[12];
    const float* head_w  = (const float*)d_in[13];
    const float* head_b  = (const float*)d_in[14];

    float* ws = (float*)d_ws;
    float* mean_w = ws;                          // 256
    float* std_w  = ws + 256;                    // 256
    float* wsum_w = ws + 512;                    // 512
    float* enc_w  = ws + 1024;                   // 224*2048
    float* q_w    = enc_w + (size_t)BN_ * 2048;  // 224*16384
    float* kv_w   = q_w + (size_t)BN_ * L_ * HF_;// 2 MB region, reused for bf16 K/V^T
    float* o32_w  = kv_w + (size_t)S_ * 512;     // 224*2048
    float* cp_w   = o32_w + (size_t)BN_ * 2048;  // 25*1000*512 (51.2 MB)
    float* rep_w  = cp_w;                        // alias: cp dead after k_red
    ushort* et_w  = (ushort*)(cp_w + (size_t)KSPLIT2 * S_ * 512);  // 512*32000 bf16
    ushort* wkv_w = et_w + (size_t)512 * V_;                       // 512*4096 bf16
    ushort* kb_w  = (ushort*)kv_w;               // [1024][256] bf16 (512 KB)
    ushort* vt_w  = kb_w + (size_t)SP_ * HF_;    // [256][1024] bf16 (512 KB)

    k_stats<<<BN_, 256, 0, stream>>>(x_enc, mean_w, std_w);
    k_wsum<<<512, 256, 0, stream>>>(wk, wv, wsum_w);
    k_enc<<<BN_, 256, 0, stream>>>(x_enc, conv_w, mean_w, std_w, enc_w);
    k_q<<<BN_, 256, 0, stream>>>(enc_w, wq, bq, q_w);
    k_cvt_wkv<<<(512 * DLLM_ / 8) / 256, 256, 0, stream>>>(wk, wv, wkv_w);
    k_gemm1<<<dim3(2, V_ / 128), 512, 0, stream>>>(word_emb, wkv_w, et_w);
    k_gemm2<<<dim3(8, 4, KSPLIT2), 256, 0, stream>>>(map_w, et_w, cp_w);
    k_red<<<(SP_ * 512) / 256, 256, 0, stream>>>(cp_w, map_b, wsum_w, bk, bv, kb_w, vt_w);
    k_attn<<<dim3(NH_, BN_), 256, 0, stream>>>(q_w, kb_w, vt_w, rep_w);
    k_out<<<BN_, 256, 0, stream>>>(rep_w, wo, bo, o32_w);
    k_head<<<BN_, 256, 0, stream>>>(o32_w, head_w, head_b, mean_w, std_w, (float*)d_out);
}